// Round 1
// baseline (6602.999 us; speedup 1.0000x reference)
//
#include <hip/hip_runtime.h>
#include <math.h>

#define CC 256
#define HIMG 128
#define WIMG 128
#define BB 8
#define PP 32
#define NPIX 4096   // 64*64 per patch
#define HS 64

// ---------------- wave reduce helpers (wave64) ----------------
static __device__ __forceinline__ float wave_max(float v){
  #pragma unroll
  for (int o=32;o>0;o>>=1) v = fmaxf(v, __shfl_down(v,o));
  return v;
}
static __device__ __forceinline__ float wave_sum(float v){
  #pragma unroll
  for (int o=32;o>0;o>>=1) v += __shfl_down(v,o);
  return v;
}

// ---------------- 1. adaptive max pool to (B,C,2,2) ----------------
__global__ void k_pool(const float* __restrict__ x, float* __restrict__ pooled){
  int blk = blockIdx.x;            // B*C*4 blocks
  int sj = blk & 1, si = (blk>>1)&1;
  int bc = blk >> 2;               // b*C + c
  const float* base = x + (size_t)bc*HIMG*WIMG + (size_t)(si*64)*WIMG + sj*64;
  float m = -INFINITY;
  for (int e = threadIdx.x; e < 4096; e += 256){
    int r = e >> 6, col = e & 63;
    m = fmaxf(m, base[r*WIMG + col]);
  }
  m = wave_max(m);
  __shared__ float sm[4];
  if ((threadIdx.x & 63) == 0) sm[threadIdx.x>>6] = m;
  __syncthreads();
  if (threadIdx.x == 0){
    m = fmaxf(fmaxf(sm[0],sm[1]), fmaxf(sm[2],sm[3]));
    pooled[(size_t)bc*4 + si*2 + sj] = m;
  }
}

// ---------------- 2. nonlocal block on pooled + sigmoid -> gca (B,C,2,2) ----------------
__global__ void k_gca(const float* __restrict__ pooled,
                      const float* __restrict__ nq_w, const float* __restrict__ nq_b,
                      const float* __restrict__ nk_w, const float* __restrict__ nk_b,
                      const float* __restrict__ nv_w, const float* __restrict__ nv_b,
                      const float* __restrict__ nlg, float* __restrict__ gca){
  int b = blockIdx.x;
  int t = threadIdx.x;             // channel
  __shared__ float pld[256][4];
  __shared__ float qs[8][4], ks2[8][4], attn[4][4];
  const float* pb = pooled + (size_t)b*CC*4;
  #pragma unroll
  for (int n=0;n<4;n++) pld[t][n] = pb[t*4+n];
  __syncthreads();
  if (t < 32){
    int j = t>>2, n = t&3;
    float aq = 0.f, ak = 0.f;
    for (int c2=0;c2<256;c2++){ float pv = pld[c2][n]; aq += nq_w[j*256+c2]*pv; ak += nk_w[j*256+c2]*pv; }
    qs[j][n] = aq + nq_b[j];
    ks2[j][n] = ak + nk_b[j];
  }
  __syncthreads();
  if (t < 4){
    int n = t;
    float e[4]; float mx = -INFINITY;
    for (int m2=0;m2<4;m2++){ float s=0.f; for (int j=0;j<8;j++) s += qs[j][n]*ks2[j][m2]; e[m2]=s; mx=fmaxf(mx,s); }
    float den=0.f;
    for (int m2=0;m2<4;m2++){ e[m2] = expf(e[m2]-mx); den += e[m2]; }
    for (int m2=0;m2<4;m2++) attn[n][m2] = e[m2]/den;
  }
  __syncthreads();
  float vv[4];
  #pragma unroll
  for (int m2=0;m2<4;m2++){
    float s = nv_b[t];
    for (int c2=0;c2<256;c2++) s += nv_w[(size_t)t*256+c2]*pld[c2][m2];
    vv[m2] = s;
  }
  float g = *nlg;
  #pragma unroll
  for (int n=0;n<4;n++){
    float o = 0.f;
    #pragma unroll
    for (int m2=0;m2<4;m2++) o += vv[m2]*attn[n][m2];
    float val = g*o + pld[t][n];
    gca[(size_t)b*CC*4 + t*4 + n] = 1.0f/(1.0f + expf(-val));
  }
}

// ---------------- 3. extract patches + rotate -45 (nearest, zero fill) ----------------
__global__ void k_rot_in(const float* __restrict__ x, float* __restrict__ xr){
  const float th = -45.0f * 0.017453292519943295f;
  const float cth = cosf(th), sth = sinf(th);
  size_t total = (size_t)PP*CC*NPIX;
  for (size_t i = (size_t)blockIdx.x*blockDim.x + threadIdx.x; i < total; i += (size_t)gridDim.x*blockDim.x){
    int xo = (int)(i & 63), yo = (int)((i>>6)&63);
    int pc = (int)(i >> 12);
    int p = pc >> 8;
    float fx = (float)xo - 31.5f, fy = (float)yo - 31.5f;
    float sx = cth*fx + sth*fy + 31.5f;
    float sy = cth*fy - sth*fx + 31.5f;
    float rx = rintf(sx), ry = rintf(sy);
    float val = 0.f;
    if (rx >= 0.f && rx < 64.f && ry >= 0.f && ry < 64.f){
      int ix = (int)rx, iy = (int)ry;
      int c = pc & 255;
      int b = p>>2, si = (p>>1)&1, sj = p&1;
      val = x[((size_t)(b*CC + c)*HIMG + si*64 + iy)*WIMG + sj*64 + ix];
    }
    xr[i] = val;
  }
}

// ---------------- 4. q,k 1x1 projection (view0: patch view of x; view1: contiguous) ----------------
__global__ __launch_bounds__(256,2) void k_proj_qk(const float* __restrict__ X, int view,
    const float* __restrict__ wq, const float* __restrict__ bq,
    const float* __restrict__ wk, const float* __restrict__ bk,
    float* __restrict__ q, float* __restrict__ k){
  __shared__ float wl[16384];       // [c][64]  (o<32: wq, o>=32: wk)
  int bid = blockIdx.x;             // 32p * 16chunk
  int p = bid >> 4, chunk = bid & 15;
  int tid = threadIdx.x;
  for (int idx = tid; idx < 16384; idx += 256){
    int o = idx & 63, c = idx >> 6;
    wl[idx] = (o < 32) ? wq[o*CC + c] : wk[(o-32)*CC + c];
  }
  __syncthreads();
  int og = tid >> 7;                // 0 -> q outputs, 1 -> k outputs
  int slot = tid & 127;
  int px0 = chunk*256 + slot*2;
  size_t base; int cstride;
  if (view == 0){
    int b = p>>2, si = (p>>1)&1, sj = p&1;
    base = (size_t)b*CC*HIMG*WIMG + (size_t)(si*64 + (px0>>6))*WIMG + sj*64 + (px0&63);
    cstride = HIMG*WIMG;
  } else {
    base = (size_t)p*CC*NPIX + px0;
    cstride = NPIX;
  }
  float acc0[32], acc1[32];
  #pragma unroll
  for (int i=0;i<32;i++){ acc0[i]=0.f; acc1[i]=0.f; }
  const float* xp = X + base;
  for (int c=0;c<CC;c++){
    float xv0 = xp[0], xv1 = xp[1];
    xp += cstride;
    const float4* wp = (const float4*)&wl[c*64 + og*32];
    #pragma unroll
    for (int o4=0;o4<8;o4++){
      float4 w4 = wp[o4];
      acc0[o4*4+0] += w4.x*xv0; acc0[o4*4+1] += w4.y*xv0; acc0[o4*4+2] += w4.z*xv0; acc0[o4*4+3] += w4.w*xv0;
      acc1[o4*4+0] += w4.x*xv1; acc1[o4*4+1] += w4.y*xv1; acc1[o4*4+2] += w4.z*xv1; acc1[o4*4+3] += w4.w*xv1;
    }
  }
  float* outp = og ? k : q;
  const float* bias = og ? bk : bq;
  #pragma unroll
  for (int o=0;o<32;o++){
    float bsv = bias[o];
    size_t oi = ((size_t)p*32 + o)*NPIX + px0;
    outp[oi]   = acc0[o] + bsv;
    outp[oi+1] = acc1[o] + bsv;
  }
}

// ---------------- 5. v 1x1 projection (256 outputs, 4 o-chunks) ----------------
__global__ __launch_bounds__(256,2) void k_proj_v(const float* __restrict__ X, int view,
    const float* __restrict__ wv, const float* __restrict__ bv, float* __restrict__ vout){
  __shared__ float wl[16384];       // [c][64] for this o-chunk
  int bid = blockIdx.x;             // p*64 + chunk*4 + oc
  int oc = bid & 3, chunk = (bid>>2) & 15, p = bid >> 6;
  int tid = threadIdx.x;
  for (int idx = tid; idx < 16384; idx += 256){
    int o = idx & 63, c = idx >> 6;
    wl[idx] = wv[(size_t)(oc*64 + o)*CC + c];
  }
  __syncthreads();
  int og = tid >> 7;
  int slot = tid & 127;
  int px0 = chunk*256 + slot*2;
  size_t base; int cstride;
  if (view == 0){
    int b = p>>2, si = (p>>1)&1, sj = p&1;
    base = (size_t)b*CC*HIMG*WIMG + (size_t)(si*64 + (px0>>6))*WIMG + sj*64 + (px0&63);
    cstride = HIMG*WIMG;
  } else {
    base = (size_t)p*CC*NPIX + px0;
    cstride = NPIX;
  }
  float acc0[32], acc1[32];
  #pragma unroll
  for (int i=0;i<32;i++){ acc0[i]=0.f; acc1[i]=0.f; }
  const float* xp = X + base;
  for (int c=0;c<CC;c++){
    float xv0 = xp[0], xv1 = xp[1];
    xp += cstride;
    const float4* wp = (const float4*)&wl[c*64 + og*32];
    #pragma unroll
    for (int o4=0;o4<8;o4++){
      float4 w4 = wp[o4];
      acc0[o4*4+0] += w4.x*xv0; acc0[o4*4+1] += w4.y*xv0; acc0[o4*4+2] += w4.z*xv0; acc0[o4*4+3] += w4.w*xv0;
      acc1[o4*4+0] += w4.x*xv1; acc1[o4*4+1] += w4.y*xv1; acc1[o4*4+2] += w4.z*xv1; acc1[o4*4+3] += w4.w*xv1;
    }
  }
  #pragma unroll
  for (int i=0;i<32;i++){
    int o = oc*64 + og*32 + i;
    float bsv = bv[o];
    size_t oi = ((size_t)p*CC + o)*NPIX + px0;
    vout[oi]   = acc0[i] + bsv;
    vout[oi+1] = acc1[i] + bsv;
  }
}

// ---------------- 6. eH logits (column attention, diagonal masked) ----------------
__global__ void k_eH(const float* __restrict__ q, const float* __restrict__ k, float* __restrict__ att){
  int bid = blockIdx.x;                       // 2048; XCD-bijective swizzle (2048%8==0)
  int lb = (bid & 7)*256 + (bid >> 3);
  int p = lb >> 6, w = lb & 63;
  __shared__ float Q[2048], K[2048];          // [c][h]
  int tid = threadIdx.x;
  for (int idx = tid; idx < 2048; idx += 256){
    int h = idx & 63, c = idx >> 6;
    size_t a = ((size_t)p*32 + c)*NPIX + h*64 + w;
    Q[idx] = q[a];
    K[idx] = k[a];
  }
  __syncthreads();
  int h = tid & 63, gq = tid >> 6;
  float e[16];
  #pragma unroll
  for (int i=0;i<16;i++) e[i] = 0.f;
  for (int c=0;c<32;c++){
    float qv = Q[c*64 + h];
    const float4* kp = (const float4*)&K[c*64 + gq*16];
    #pragma unroll
    for (int i4=0;i4<4;i4++){
      float4 k4 = kp[i4];
      e[i4*4+0] += qv*k4.x; e[i4*4+1] += qv*k4.y; e[i4*4+2] += qv*k4.z; e[i4*4+3] += qv*k4.w;
    }
  }
  #pragma unroll
  for (int i=0;i<16;i++){
    int g = gq*16 + i;
    if (g == h) e[i] = -1e30f;
  }
  float4* op = (float4*)(att + (((size_t)p*64 + h)*64 + w)*128 + gq*16);
  op[0] = make_float4(e[0],e[1],e[2],e[3]);
  op[1] = make_float4(e[4],e[5],e[6],e[7]);
  op[2] = make_float4(e[8],e[9],e[10],e[11]);
  op[3] = make_float4(e[12],e[13],e[14],e[15]);
}

// ---------------- 7. eW logits (row attention) ----------------
__global__ void k_eW(const float* __restrict__ q, const float* __restrict__ k, float* __restrict__ att){
  int bid = blockIdx.x;
  int p = bid >> 6, h = bid & 63;
  __shared__ float Q[2048], K[2048];          // [c][w]
  int tid = threadIdx.x;
  for (int idx = tid; idx < 2048; idx += 256){
    int wcol = idx & 63, c = idx >> 6;
    size_t a = ((size_t)p*32 + c)*NPIX + h*64 + wcol;
    Q[idx] = q[a];
    K[idx] = k[a];
  }
  __syncthreads();
  int wcol = tid & 63, jq = tid >> 6;
  float e[16];
  #pragma unroll
  for (int i=0;i<16;i++) e[i] = 0.f;
  for (int c=0;c<32;c++){
    float qv = Q[c*64 + wcol];
    const float4* kp = (const float4*)&K[c*64 + jq*16];
    #pragma unroll
    for (int i4=0;i4<4;i4++){
      float4 k4 = kp[i4];
      e[i4*4+0] += qv*k4.x; e[i4*4+1] += qv*k4.y; e[i4*4+2] += qv*k4.z; e[i4*4+3] += qv*k4.w;
    }
  }
  float4* op = (float4*)(att + (((size_t)p*64 + h)*64 + wcol)*128 + 64 + jq*16);
  op[0] = make_float4(e[0],e[1],e[2],e[3]);
  op[1] = make_float4(e[4],e[5],e[6],e[7]);
  op[2] = make_float4(e[8],e[9],e[10],e[11]);
  op[3] = make_float4(e[12],e[13],e[14],e[15]);
}

// ---------------- 8. softmax over 128 logits per (p,h,w) ----------------
__global__ void k_softmax(float* __restrict__ att){
  int row = blockIdx.x*4 + (threadIdx.x >> 6);    // 131072 rows
  int lane = threadIdx.x & 63;
  float* rp = att + (size_t)row*128;
  float v0 = rp[lane], v1 = rp[lane+64];
  float m = wave_max(fmaxf(v0,v1));
  m = __shfl(m, 0);
  float e0 = expf(v0 - m), e1 = expf(v1 - m);
  float s = wave_sum(e0 + e1);
  s = __shfl(s, 0);
  rp[lane]    = e0 / s;
  rp[lane+64] = e1 / s;
}

// ---------------- 9. oW: row-attention output (writes/initializes out) ----------------
__global__ __launch_bounds__(256) void k_oW(const float* __restrict__ v, const float* __restrict__ att, float* __restrict__ out){
  int bid = blockIdx.x;
  int p = bid >> 6, h = bid & 63;
  __shared__ float A[4096];                     // [j][w]
  int tid = threadIdx.x;
  size_t base_ph = ((size_t)p*64 + h)*8192;     // att[p][h][w][*] = base + w*128
  for (int idx = tid; idx < 4096; idx += 256){
    int wc = idx & 63, j = idx >> 6;
    A[idx] = att[base_ph + (size_t)wc*128 + 64 + j];
  }
  __syncthreads();
  int wg = tid >> 7, cp = tid & 127, c0 = cp*2;
  const float* vp0 = v + ((size_t)p*CC + c0)*NPIX + (size_t)h*64;
  float acc0[32], acc1[32];
  #pragma unroll
  for (int i=0;i<32;i++){ acc0[i]=0.f; acc1[i]=0.f; }
  for (int j=0;j<64;j++){
    float va  = vp0[j];
    float vb2 = vp0[NPIX + j];
    const float4* ap = (const float4*)&A[j*64 + wg*32];
    #pragma unroll
    for (int i4=0;i4<8;i4++){
      float4 a4 = ap[i4];
      acc0[i4*4+0] += va*a4.x;  acc0[i4*4+1] += va*a4.y;  acc0[i4*4+2] += va*a4.z;  acc0[i4*4+3] += va*a4.w;
      acc1[i4*4+0] += vb2*a4.x; acc1[i4*4+1] += vb2*a4.y; acc1[i4*4+2] += vb2*a4.z; acc1[i4*4+3] += vb2*a4.w;
    }
  }
  float* o0 = out + ((size_t)p*CC + c0)*NPIX + (size_t)h*64 + wg*32;
  float4* o04 = (float4*)o0;
  float4* o14 = (float4*)(o0 + NPIX);
  #pragma unroll
  for (int i4=0;i4<8;i4++){
    o04[i4] = make_float4(acc0[i4*4],acc0[i4*4+1],acc0[i4*4+2],acc0[i4*4+3]);
    o14[i4] = make_float4(acc1[i4*4],acc1[i4*4+1],acc1[i4*4+2],acc1[i4*4+3]);
  }
}

// ---------------- 10. oH: column-attention output (accumulates into out) ----------------
__global__ __launch_bounds__(256) void k_oH(const float* __restrict__ v, const float* __restrict__ att, float* __restrict__ out){
  int bid = blockIdx.x;
  int lb = (bid & 7)*256 + (bid >> 3);          // XCD swizzle so w-neighbors share an L2
  int p = lb >> 6, w = lb & 63;
  __shared__ float A2[4096];                    // [g][h]
  int tid = threadIdx.x;
  size_t base_pw = (size_t)p*524288 + (size_t)w*128;  // att[p][h][w][g] = base + h*8192 + g
  for (int idx = tid; idx < 4096; idx += 256){
    int hh = idx & 63, g = idx >> 6;
    A2[idx] = att[base_pw + (size_t)hh*8192 + g];
  }
  __syncthreads();
  int hg = tid >> 7, cp = tid & 127, c0 = cp*2;
  const float* vp0 = v + ((size_t)p*CC + c0)*NPIX + w;
  float acc0[32], acc1[32];
  #pragma unroll
  for (int i=0;i<32;i++){ acc0[i]=0.f; acc1[i]=0.f; }
  for (int g=0; g<64; g++){
    float va  = vp0[(size_t)g*64];
    float vb2 = vp0[NPIX + (size_t)g*64];
    const float4* ap = (const float4*)&A2[g*64 + hg*32];
    #pragma unroll
    for (int i4=0;i4<8;i4++){
      float4 a4 = ap[i4];
      acc0[i4*4+0] += va*a4.x;  acc0[i4*4+1] += va*a4.y;  acc0[i4*4+2] += va*a4.z;  acc0[i4*4+3] += va*a4.w;
      acc1[i4*4+0] += vb2*a4.x; acc1[i4*4+1] += vb2*a4.y; acc1[i4*4+2] += vb2*a4.z; acc1[i4*4+3] += vb2*a4.w;
    }
  }
  float* o0 = out + ((size_t)p*CC + c0)*NPIX + w;
  #pragma unroll
  for (int i=0;i<32;i++){
    int hh = hg*32 + i;
    o0[(size_t)hh*64]        += acc0[i];
    o0[NPIX + (size_t)hh*64] += acc1[i];
  }
}

// ---------------- 11. combine: ctx = (g1*o1 + rot45(g2*o2) + x) * gate ----------------
__global__ void k_combine(const float* __restrict__ x, const float* __restrict__ o2,
                          const float* __restrict__ gca, const float* __restrict__ g1p,
                          const float* __restrict__ g2p, float* __restrict__ o1){
  int pc = blockIdx.x;                 // p*256 + c
  int p = pc >> 8, c = pc & 255;
  int b = p>>2, si = (p>>1)&1, sj = p&1;
  float g1 = *g1p, g2 = *g2p;
  float gate = gca[((size_t)(b*CC + c)*2 + si)*2 + sj];
  const float th = 45.0f * 0.017453292519943295f;
  const float cth = cosf(th), sth = sinf(th);
  const float* xbase = x + ((size_t)(b*CC + c)*HIMG + si*64)*WIMG + sj*64;
  size_t pbase = (size_t)pc*NPIX;
  for (int e = threadIdx.x; e < NPIX; e += 256){
    int xo = e & 63, yo = e >> 6;
    float fx = (float)xo - 31.5f, fy = (float)yo - 31.5f;
    float sx = cth*fx + sth*fy + 31.5f;
    float sy = cth*fy - sth*fx + 31.5f;
    float rx = rintf(sx), ry = rintf(sy);
    float o2v = 0.f;
    if (rx >= 0.f && rx < 64.f && ry >= 0.f && ry < 64.f)
      o2v = g2 * o2[pbase + (size_t)((int)ry)*64 + (int)rx];
    float val = g1*o1[pbase + e] + o2v + xbase[(size_t)yo*WIMG + xo];
    o1[pbase + e] = val * gate;
  }
}

// ---------------- 12. 3x3 conv + BN(eval) + gamma*y + x residual + relu ----------------
__global__ __launch_bounds__(256) void k_conv(const float* __restrict__ ctx, const float* __restrict__ x,
    const float* __restrict__ cw, const float* __restrict__ cb,
    const float* __restrict__ bnw, const float* __restrict__ bnb,
    const float* __restrict__ bnm, const float* __restrict__ bnv,
    const float* __restrict__ gmp, float* __restrict__ out){
  int bid = blockIdx.x;               // b*256 + coc*64 + pxb
  int pxb = bid & 63, coc = (bid>>6)&3, b = bid >> 8;
  int tid = threadIdx.x;
  int cog = tid >> 7;                 // 0/1 : co half
  int slot = tid & 127;               // 2 px each
  int px0 = pxb*256 + slot*2;
  int Y = px0 >> 7, X0 = px0 & 127;   // X0 even -> pair stays in row
  __shared__ float wl[16384];         // [ci][64co] for current (dy,dx)
  float acc0[32], acc1[32];
  #pragma unroll
  for (int i=0;i<32;i++){ acc0[i]=0.f; acc1[i]=0.f; }
  for (int k9=0;k9<9;k9++){
    int dy = k9/3 - 1, dx = k9%3 - 1;
    __syncthreads();
    for (int idx = tid; idx < 16384; idx += 256){
      int co = idx & 63, ci = idx >> 6;
      wl[idx] = cw[(((size_t)(coc*64 + co)*CC + ci)*3 + (dy+1))*3 + (dx+1)];
    }
    __syncthreads();
    int Ys = Y + dy;
    bool vy = (unsigned)Ys < 128u;
    int Xs0 = X0 + dx, Xs1 = Xs0 + 1;
    bool v0 = vy && ((unsigned)Xs0 < 128u);
    bool v1 = vy && ((unsigned)Xs1 < 128u);
    const float* p0 = ctx; const float* p1 = ctx;
    if (v0){ int pp = (b<<2) | (((Ys>>6)&1)<<1) | ((Xs0>>6)&1);
             p0 = ctx + (size_t)pp*CC*NPIX + (size_t)(Ys&63)*64 + (Xs0&63); }
    if (v1){ int pp = (b<<2) | (((Ys>>6)&1)<<1) | ((Xs1>>6)&1);
             p1 = ctx + (size_t)pp*CC*NPIX + (size_t)(Ys&63)*64 + (Xs1&63); }
    for (int ci=0; ci<CC; ci++){
      float xv0 = v0 ? p0[(size_t)ci*NPIX] : 0.f;
      float xv1 = v1 ? p1[(size_t)ci*NPIX] : 0.f;
      const float4* wp = (const float4*)&wl[ci*64 + cog*32];
      #pragma unroll
      for (int o4=0;o4<8;o4++){
        float4 w4 = wp[o4];
        acc0[o4*4+0] += w4.x*xv0; acc0[o4*4+1] += w4.y*xv0; acc0[o4*4+2] += w4.z*xv0; acc0[o4*4+3] += w4.w*xv0;
        acc1[o4*4+0] += w4.x*xv1; acc1[o4*4+1] += w4.y*xv1; acc1[o4*4+2] += w4.z*xv1; acc1[o4*4+3] += w4.w*xv1;
      }
    }
  }
  float gm = *gmp;
  #pragma unroll
  for (int i=0;i<32;i++){
    int co = coc*64 + cog*32 + i;
    float scale = bnw[co] / sqrtf(bnv[co] + 1e-5f);
    float sh = bnb[co] - bnm[co]*scale;
    size_t xi = ((size_t)(b*CC + co)*HIMG + Y)*WIMG + X0;
    float y0 = (acc0[i] + cb[co])*scale + sh;
    float y1 = (acc1[i] + cb[co])*scale + sh;
    out[xi]   = fmaxf(gm*y0 + x[xi],   0.f);
    out[xi+1] = fmaxf(gm*y1 + x[xi+1], 0.f);
  }
}

// ---------------- launcher ----------------
extern "C" void kernel_launch(void* const* d_in, const int* in_sizes, int n_in,
                              void* d_out, int out_size, void* d_ws, size_t ws_size,
                              hipStream_t stream){
  (void)in_sizes; (void)n_in; (void)out_size; (void)ws_size;
  const float* x   = (const float*)d_in[0];
  const float* wq  = (const float*)d_in[1];
  const float* bq  = (const float*)d_in[2];
  const float* wk  = (const float*)d_in[3];
  const float* bk  = (const float*)d_in[4];
  const float* wv  = (const float*)d_in[5];
  const float* bv  = (const float*)d_in[6];
  const float* g1  = (const float*)d_in[7];
  const float* g2  = (const float*)d_in[8];
  const float* nq_w= (const float*)d_in[9];
  const float* nq_b= (const float*)d_in[10];
  const float* nk_w= (const float*)d_in[11];
  const float* nk_b= (const float*)d_in[12];
  const float* nv_w= (const float*)d_in[13];
  const float* nv_b= (const float*)d_in[14];
  const float* nlg = (const float*)d_in[15];
  const float* cw  = (const float*)d_in[16];
  const float* cb  = (const float*)d_in[17];
  const float* bnw = (const float*)d_in[18];
  const float* bnb = (const float*)d_in[19];
  const float* bnm = (const float*)d_in[20];
  const float* bnv = (const float*)d_in[21];
  const float* gam = (const float*)d_in[22];

  // ws layout (floats); total 125,845,504 floats ~= 480 MB
  float* ws  = (float*)d_ws;
  float* o1  = ws;                    // 33,554,432  : branch1 out -> ctx
  float* b2  = ws + 33554432;         // 33,554,432  : xr -> branch2 out
  float* vb  = ws + 67108864;         // 33,554,432  : v (per branch)
  float* att = ws + 100663296;        // 16,777,216  : logits/att (per branch)
  float* qb  = ws + 117440512;        //  4,194,304
  float* kb  = ws + 121634816;        //  4,194,304
  float* pooled = ws + 125829120;     //  8,192
  float* gcab   = ws + 125837312;     //  8,192

  k_pool<<<8192,256,0,stream>>>(x, pooled);
  k_gca<<<8,256,0,stream>>>(pooled, nq_w,nq_b, nk_w,nk_b, nv_w,nv_b, nlg, gcab);
  k_rot_in<<<8192,256,0,stream>>>(x, b2);

  // branch 1: criss-cross on original patches (view 0 = strided patch view of x)
  k_proj_qk<<<512,256,0,stream>>>(x, 0, wq,bq, wk,bk, qb, kb);
  k_eH<<<2048,256,0,stream>>>(qb, kb, att);
  k_eW<<<2048,256,0,stream>>>(qb, kb, att);
  k_softmax<<<32768,256,0,stream>>>(att);
  k_proj_v<<<2048,256,0,stream>>>(x, 0, wv, bv, vb);
  k_oW<<<2048,256,0,stream>>>(vb, att, o1);
  k_oH<<<2048,256,0,stream>>>(vb, att, o1);

  // branch 2: criss-cross on rotated patches (view 1 = contiguous xr in b2)
  k_proj_qk<<<512,256,0,stream>>>(b2, 1, wq,bq, wk,bk, qb, kb);
  k_eH<<<2048,256,0,stream>>>(qb, kb, att);
  k_eW<<<2048,256,0,stream>>>(qb, kb, att);
  k_softmax<<<32768,256,0,stream>>>(att);
  k_proj_v<<<2048,256,0,stream>>>(b2, 1, wv, bv, vb);
  k_oW<<<2048,256,0,stream>>>(vb, att, b2);   // overwrites xr (dead after projections)
  k_oH<<<2048,256,0,stream>>>(vb, att, b2);

  k_combine<<<8192,256,0,stream>>>(x, b2, gcab, g1, g2, o1);
  k_conv<<<2048,256,0,stream>>>(o1, x, cw, cb, bnw, bnb, bnm, bnv, gam, (float*)d_out);
}

// Round 3
// 3666.396 us; speedup vs baseline: 1.8010x; 1.8010x over previous
//
#include <hip/hip_runtime.h>
#include <math.h>

#define CC 256
#define HIMG 128
#define WIMG 128
#define BB 8
#define PP 32
#define NPIX 4096   // 64*64 per patch
#define HS 64

typedef short bf16x8 __attribute__((ext_vector_type(8)));
typedef float f32x4 __attribute__((ext_vector_type(4)));
typedef unsigned short u16x8 __attribute__((ext_vector_type(8)));

static __device__ __forceinline__ unsigned short f2bf(float f){
  unsigned u = __float_as_uint(f);
  unsigned r = (u + 0x7fffu + ((u >> 16) & 1u)) >> 16;
  return (unsigned short)r;
}

// ---------------- wave reduce helpers (wave64) ----------------
static __device__ __forceinline__ float wave_max(float v){
  #pragma unroll
  for (int o=32;o>0;o>>=1) v = fmaxf(v, __shfl_down(v,o));
  return v;
}
static __device__ __forceinline__ float wave_sum(float v){
  #pragma unroll
  for (int o=32;o>0;o>>=1) v += __shfl_down(v,o);
  return v;
}

// ---------------- 1. adaptive max pool to (B,C,2,2) ----------------
__global__ void k_pool(const float* __restrict__ x, float* __restrict__ pooled){
  int blk = blockIdx.x;            // B*C*4 blocks
  int sj = blk & 1, si = (blk>>1)&1;
  int bc = blk >> 2;               // b*C + c
  const float* base = x + (size_t)bc*HIMG*WIMG + (size_t)(si*64)*WIMG + sj*64;
  float m = -INFINITY;
  for (int e = threadIdx.x; e < 4096; e += 256){
    int r = e >> 6, col = e & 63;
    m = fmaxf(m, base[r*WIMG + col]);
  }
  m = wave_max(m);
  __shared__ float sm[4];
  if ((threadIdx.x & 63) == 0) sm[threadIdx.x>>6] = m;
  __syncthreads();
  if (threadIdx.x == 0){
    m = fmaxf(fmaxf(sm[0],sm[1]), fmaxf(sm[2],sm[3]));
    pooled[(size_t)bc*4 + si*2 + sj] = m;
  }
}

// ---------------- 2. nonlocal block on pooled + sigmoid -> gca (B,C,2,2) ----------------
__global__ void k_gca(const float* __restrict__ pooled,
                      const float* __restrict__ nq_w, const float* __restrict__ nq_b,
                      const float* __restrict__ nk_w, const float* __restrict__ nk_b,
                      const float* __restrict__ nv_w, const float* __restrict__ nv_b,
                      const float* __restrict__ nlg, float* __restrict__ gca){
  int b = blockIdx.x;
  int t = threadIdx.x;             // channel
  __shared__ float pld[256][4];
  __shared__ float qs[8][4], ks2[8][4], attn[4][4];
  const float* pb = pooled + (size_t)b*CC*4;
  #pragma unroll
  for (int n=0;n<4;n++) pld[t][n] = pb[t*4+n];
  __syncthreads();
  if (t < 32){
    int j = t>>2, n = t&3;
    float aq = 0.f, ak = 0.f;
    for (int c2=0;c2<256;c2++){ float pv = pld[c2][n]; aq += nq_w[j*256+c2]*pv; ak += nk_w[j*256+c2]*pv; }
    qs[j][n] = aq + nq_b[j];
    ks2[j][n] = ak + nk_b[j];
  }
  __syncthreads();
  if (t < 4){
    int n = t;
    float e[4]; float mx = -INFINITY;
    for (int m2=0;m2<4;m2++){ float s=0.f; for (int j=0;j<8;j++) s += qs[j][n]*ks2[j][m2]; e[m2]=s; mx=fmaxf(mx,s); }
    float den=0.f;
    for (int m2=0;m2<4;m2++){ e[m2] = expf(e[m2]-mx); den += e[m2]; }
    for (int m2=0;m2<4;m2++) attn[n][m2] = e[m2]/den;
  }
  __syncthreads();
  float vv[4];
  #pragma unroll
  for (int m2=0;m2<4;m2++){
    float s = nv_b[t];
    for (int c2=0;c2<256;c2++) s += nv_w[(size_t)t*256+c2]*pld[c2][m2];
    vv[m2] = s;
  }
  float g = *nlg;
  #pragma unroll
  for (int n=0;n<4;n++){
    float o = 0.f;
    #pragma unroll
    for (int m2=0;m2<4;m2++) o += vv[m2]*attn[n][m2];
    float val = g*o + pld[t][n];
    gca[(size_t)b*CC*4 + t*4 + n] = 1.0f/(1.0f + expf(-val));
  }
}

// ---------------- 3. extract patches + rotate -45 (nearest, zero fill) ----------------
__global__ void k_rot_in(const float* __restrict__ x, float* __restrict__ xr){
  const float th = -45.0f * 0.017453292519943295f;
  const float cth = cosf(th), sth = sinf(th);
  size_t total = (size_t)PP*CC*NPIX;
  for (size_t i = (size_t)blockIdx.x*blockDim.x + threadIdx.x; i < total; i += (size_t)gridDim.x*blockDim.x){
    int xo = (int)(i & 63), yo = (int)((i>>6)&63);
    int pc = (int)(i >> 12);
    int p = pc >> 8;
    float fx = (float)xo - 31.5f, fy = (float)yo - 31.5f;
    float sx = cth*fx + sth*fy + 31.5f;
    float sy = cth*fy - sth*fx + 31.5f;
    float rx = rintf(sx), ry = rintf(sy);
    float val = 0.f;
    if (rx >= 0.f && rx < 64.f && ry >= 0.f && ry < 64.f){
      int ix = (int)rx, iy = (int)ry;
      int c = pc & 255;
      int b = p>>2, si = (p>>1)&1, sj = p&1;
      val = x[((size_t)(b*CC + c)*HIMG + si*64 + iy)*WIMG + sj*64 + ix];
    }
    xr[i] = val;
  }
}

// ---------------- 4. q,k 1x1 projection (view0: patch view of x; view1: contiguous) ----------------
__global__ __launch_bounds__(256,2) void k_proj_qk(const float* __restrict__ X, int view,
    const float* __restrict__ wq, const float* __restrict__ bq,
    const float* __restrict__ wk, const float* __restrict__ bk,
    float* __restrict__ q, float* __restrict__ k){
  __shared__ float wl[16384];       // [c][64]  (o<32: wq, o>=32: wk)
  int bid = blockIdx.x;             // 32p * 16chunk
  int p = bid >> 4, chunk = bid & 15;
  int tid = threadIdx.x;
  for (int idx = tid; idx < 16384; idx += 256){
    int o = idx & 63, c = idx >> 6;
    wl[idx] = (o < 32) ? wq[o*CC + c] : wk[(o-32)*CC + c];
  }
  __syncthreads();
  int og = tid >> 7;                // 0 -> q outputs, 1 -> k outputs
  int slot = tid & 127;
  int px0 = chunk*256 + slot*2;
  size_t base; int cstride;
  if (view == 0){
    int b = p>>2, si = (p>>1)&1, sj = p&1;
    base = (size_t)b*CC*HIMG*WIMG + (size_t)(si*64 + (px0>>6))*WIMG + sj*64 + (px0&63);
    cstride = HIMG*WIMG;
  } else {
    base = (size_t)p*CC*NPIX + px0;
    cstride = NPIX;
  }
  float acc0[32], acc1[32];
  #pragma unroll
  for (int i=0;i<32;i++){ acc0[i]=0.f; acc1[i]=0.f; }
  const float* xp = X + base;
  for (int c=0;c<CC;c++){
    float xv0 = xp[0], xv1 = xp[1];
    xp += cstride;
    const float4* wp = (const float4*)&wl[c*64 + og*32];
    #pragma unroll
    for (int o4=0;o4<8;o4++){
      float4 w4 = wp[o4];
      acc0[o4*4+0] += w4.x*xv0; acc0[o4*4+1] += w4.y*xv0; acc0[o4*4+2] += w4.z*xv0; acc0[o4*4+3] += w4.w*xv0;
      acc1[o4*4+0] += w4.x*xv1; acc1[o4*4+1] += w4.y*xv1; acc1[o4*4+2] += w4.z*xv1; acc1[o4*4+3] += w4.w*xv1;
    }
  }
  float* outp = og ? k : q;
  const float* bias = og ? bk : bq;
  #pragma unroll
  for (int o=0;o<32;o++){
    float bsv = bias[o];
    size_t oi = ((size_t)p*32 + o)*NPIX + px0;
    outp[oi]   = acc0[o] + bsv;
    outp[oi+1] = acc1[o] + bsv;
  }
}

// ---------------- 5. v 1x1 projection (256 outputs, 4 o-chunks) ----------------
__global__ __launch_bounds__(256,2) void k_proj_v(const float* __restrict__ X, int view,
    const float* __restrict__ wv, const float* __restrict__ bv, float* __restrict__ vout){
  __shared__ float wl[16384];       // [c][64] for this o-chunk
  int bid = blockIdx.x;             // p*64 + chunk*4 + oc
  int oc = bid & 3, chunk = (bid>>2) & 15, p = bid >> 6;
  int tid = threadIdx.x;
  for (int idx = tid; idx < 16384; idx += 256){
    int o = idx & 63, c = idx >> 6;
    wl[idx] = wv[(size_t)(oc*64 + o)*CC + c];
  }
  __syncthreads();
  int og = tid >> 7;
  int slot = tid & 127;
  int px0 = chunk*256 + slot*2;
  size_t base; int cstride;
  if (view == 0){
    int b = p>>2, si = (p>>1)&1, sj = p&1;
    base = (size_t)b*CC*HIMG*WIMG + (size_t)(si*64 + (px0>>6))*WIMG + sj*64 + (px0&63);
    cstride = HIMG*WIMG;
  } else {
    base = (size_t)p*CC*NPIX + px0;
    cstride = NPIX;
  }
  float acc0[32], acc1[32];
  #pragma unroll
  for (int i=0;i<32;i++){ acc0[i]=0.f; acc1[i]=0.f; }
  const float* xp = X + base;
  for (int c=0;c<CC;c++){
    float xv0 = xp[0], xv1 = xp[1];
    xp += cstride;
    const float4* wp = (const float4*)&wl[c*64 + og*32];
    #pragma unroll
    for (int o4=0;o4<8;o4++){
      float4 w4 = wp[o4];
      acc0[o4*4+0] += w4.x*xv0; acc0[o4*4+1] += w4.y*xv0; acc0[o4*4+2] += w4.z*xv0; acc0[o4*4+3] += w4.w*xv0;
      acc1[o4*4+0] += w4.x*xv1; acc1[o4*4+1] += w4.y*xv1; acc1[o4*4+2] += w4.z*xv1; acc1[o4*4+3] += w4.w*xv1;
    }
  }
  #pragma unroll
  for (int i=0;i<32;i++){
    int o = oc*64 + og*32 + i;
    float bsv = bv[o];
    size_t oi = ((size_t)p*CC + o)*NPIX + px0;
    vout[oi]   = acc0[i] + bsv;
    vout[oi+1] = acc1[i] + bsv;
  }
}

// ---------------- 6. eH logits (column attention, diagonal masked) ----------------
__global__ void k_eH(const float* __restrict__ q, const float* __restrict__ k, float* __restrict__ att){
  int bid = blockIdx.x;                       // 2048; XCD-bijective swizzle (2048%8==0)
  int lb = (bid & 7)*256 + (bid >> 3);
  int p = lb >> 6, w = lb & 63;
  __shared__ float Q[2048], K[2048];          // [c][h]
  int tid = threadIdx.x;
  for (int idx = tid; idx < 2048; idx += 256){
    int h = idx & 63, c = idx >> 6;
    size_t a = ((size_t)p*32 + c)*NPIX + h*64 + w;
    Q[idx] = q[a];
    K[idx] = k[a];
  }
  __syncthreads();
  int h = tid & 63, gq = tid >> 6;
  float e[16];
  #pragma unroll
  for (int i=0;i<16;i++) e[i] = 0.f;
  for (int c=0;c<32;c++){
    float qv = Q[c*64 + h];
    const float4* kp = (const float4*)&K[c*64 + gq*16];
    #pragma unroll
    for (int i4=0;i4<4;i4++){
      float4 k4 = kp[i4];
      e[i4*4+0] += qv*k4.x; e[i4*4+1] += qv*k4.y; e[i4*4+2] += qv*k4.z; e[i4*4+3] += qv*k4.w;
    }
  }
  #pragma unroll
  for (int i=0;i<16;i++){
    int g = gq*16 + i;
    if (g == h) e[i] = -1e30f;
  }
  float4* op = (float4*)(att + (((size_t)p*64 + h)*64 + w)*128 + gq*16);
  op[0] = make_float4(e[0],e[1],e[2],e[3]);
  op[1] = make_float4(e[4],e[5],e[6],e[7]);
  op[2] = make_float4(e[8],e[9],e[10],e[11]);
  op[3] = make_float4(e[12],e[13],e[14],e[15]);
}

// ---------------- 7. eW logits (row attention) ----------------
__global__ void k_eW(const float* __restrict__ q, const float* __restrict__ k, float* __restrict__ att){
  int bid = blockIdx.x;
  int p = bid >> 6, h = bid & 63;
  __shared__ float Q[2048], K[2048];          // [c][w]
  int tid = threadIdx.x;
  for (int idx = tid; idx < 2048; idx += 256){
    int wcol = idx & 63, c = idx >> 6;
    size_t a = ((size_t)p*32 + c)*NPIX + h*64 + wcol;
    Q[idx] = q[a];
    K[idx] = k[a];
  }
  __syncthreads();
  int wcol = tid & 63, jq = tid >> 6;
  float e[16];
  #pragma unroll
  for (int i=0;i<16;i++) e[i] = 0.f;
  for (int c=0;c<32;c++){
    float qv = Q[c*64 + wcol];
    const float4* kp = (const float4*)&K[c*64 + jq*16];
    #pragma unroll
    for (int i4=0;i4<4;i4++){
      float4 k4 = kp[i4];
      e[i4*4+0] += qv*k4.x; e[i4*4+1] += qv*k4.y; e[i4*4+2] += qv*k4.z; e[i4*4+3] += qv*k4.w;
    }
  }
  float4* op = (float4*)(att + (((size_t)p*64 + h)*64 + wcol)*128 + 64 + jq*16);
  op[0] = make_float4(e[0],e[1],e[2],e[3]);
  op[1] = make_float4(e[4],e[5],e[6],e[7]);
  op[2] = make_float4(e[8],e[9],e[10],e[11]);
  op[3] = make_float4(e[12],e[13],e[14],e[15]);
}

// ---------------- 8. softmax over 128 logits per (p,h,w) ----------------
__global__ void k_softmax(float* __restrict__ att){
  int row = blockIdx.x*4 + (threadIdx.x >> 6);    // 131072 rows
  int lane = threadIdx.x & 63;
  float* rp = att + (size_t)row*128;
  float v0 = rp[lane], v1 = rp[lane+64];
  float m = wave_max(fmaxf(v0,v1));
  m = __shfl(m, 0);
  float e0 = expf(v0 - m), e1 = expf(v1 - m);
  float s = wave_sum(e0 + e1);
  s = __shfl(s, 0);
  rp[lane]    = e0 / s;
  rp[lane+64] = e1 / s;
}

// ---------------- 9. oW: row-attention output (writes/initializes out) ----------------
__global__ __launch_bounds__(256) void k_oW(const float* __restrict__ v, const float* __restrict__ att, float* __restrict__ out){
  int bid = blockIdx.x;
  int p = bid >> 6, h = bid & 63;
  __shared__ float A[4096];                     // [j][w]
  int tid = threadIdx.x;
  size_t base_ph = ((size_t)p*64 + h)*8192;     // att[p][h][w][*] = base + w*128
  for (int idx = tid; idx < 4096; idx += 256){
    int wc = idx & 63, j = idx >> 6;
    A[idx] = att[base_ph + (size_t)wc*128 + 64 + j];
  }
  __syncthreads();
  int wg = tid >> 7, cp = tid & 127, c0 = cp*2;
  const float* vp0 = v + ((size_t)p*CC + c0)*NPIX + (size_t)h*64;
  float acc0[32], acc1[32];
  #pragma unroll
  for (int i=0;i<32;i++){ acc0[i]=0.f; acc1[i]=0.f; }
  for (int j=0;j<64;j++){
    float va  = vp0[j];
    float vb2 = vp0[NPIX + j];
    const float4* ap = (const float4*)&A[j*64 + wg*32];
    #pragma unroll
    for (int i4=0;i4<8;i4++){
      float4 a4 = ap[i4];
      acc0[i4*4+0] += va*a4.x;  acc0[i4*4+1] += va*a4.y;  acc0[i4*4+2] += va*a4.z;  acc0[i4*4+3] += va*a4.w;
      acc1[i4*4+0] += vb2*a4.x; acc1[i4*4+1] += vb2*a4.y; acc1[i4*4+2] += vb2*a4.z; acc1[i4*4+3] += vb2*a4.w;
    }
  }
  float* o0 = out + ((size_t)p*CC + c0)*NPIX + (size_t)h*64 + wg*32;
  float4* o04 = (float4*)o0;
  float4* o14 = (float4*)(o0 + NPIX);
  #pragma unroll
  for (int i4=0;i4<8;i4++){
    o04[i4] = make_float4(acc0[i4*4],acc0[i4*4+1],acc0[i4*4+2],acc0[i4*4+3]);
    o14[i4] = make_float4(acc1[i4*4],acc1[i4*4+1],acc1[i4*4+2],acc1[i4*4+3]);
  }
}

// ---------------- 10. oH: column-attention output (accumulates into out) ----------------
__global__ __launch_bounds__(256) void k_oH(const float* __restrict__ v, const float* __restrict__ att, float* __restrict__ out){
  int bid = blockIdx.x;
  int lb = (bid & 7)*256 + (bid >> 3);          // XCD swizzle so w-neighbors share an L2
  int p = lb >> 6, w = lb & 63;
  __shared__ float A2[4096];                    // [g][h]
  int tid = threadIdx.x;
  size_t base_pw = (size_t)p*524288 + (size_t)w*128;  // att[p][h][w][g] = base + h*8192 + g
  for (int idx = tid; idx < 4096; idx += 256){
    int hh = idx & 63, g = idx >> 6;
    A2[idx] = att[base_pw + (size_t)hh*8192 + g];
  }
  __syncthreads();
  int hg = tid >> 7, cp = tid & 127, c0 = cp*2;
  const float* vp0 = v + ((size_t)p*CC + c0)*NPIX + w;
  float acc0[32], acc1[32];
  #pragma unroll
  for (int i=0;i<32;i++){ acc0[i]=0.f; acc1[i]=0.f; }
  for (int g=0; g<64; g++){
    float va  = vp0[(size_t)g*64];
    float vb2 = vp0[NPIX + (size_t)g*64];
    const float4* ap = (const float4*)&A2[g*64 + hg*32];
    #pragma unroll
    for (int i4=0;i4<8;i4++){
      float4 a4 = ap[i4];
      acc0[i4*4+0] += va*a4.x;  acc0[i4*4+1] += va*a4.y;  acc0[i4*4+2] += va*a4.z;  acc0[i4*4+3] += va*a4.w;
      acc1[i4*4+0] += vb2*a4.x; acc1[i4*4+1] += vb2*a4.y; acc1[i4*4+2] += vb2*a4.z; acc1[i4*4+3] += vb2*a4.w;
    }
  }
  float* o0 = out + ((size_t)p*CC + c0)*NPIX + w;
  #pragma unroll
  for (int i=0;i<32;i++){
    int hh = hg*32 + i;
    o0[(size_t)hh*64]        += acc0[i];
    o0[NPIX + (size_t)hh*64] += acc1[i];
  }
}

// ---------------- 11. weight split: cw fp32 -> [tap][co][ci] bf16 hi/lo ----------------
__global__ void k_wsplit(const float* __restrict__ cw, unsigned short* __restrict__ wh,
                         unsigned short* __restrict__ wlo){
  int idx = blockIdx.x*256 + threadIdx.x;      // 2304 blocks -> 589824
  if (idx >= 9*256*256) return;
  int tap = idx >> 16;         // 0..8
  int rem = idx & 65535;       // co*256+ci
  float w = cw[(size_t)rem*9 + tap];
  unsigned short h = f2bf(w);
  float hf = __uint_as_float((unsigned)h << 16);
  wh[idx] = h;
  wlo[idx] = f2bf(w - hf);
}

// ---------------- 12. combine: ctx = (g1*o1 + rot45(g2*o2) + x) * gate -> NHWC bf16 hi/lo ----------------
__global__ __launch_bounds__(256) void k_combine(const float* __restrict__ x, const float* __restrict__ o1,
                          const float* __restrict__ o2, const float* __restrict__ gca,
                          const float* __restrict__ g1p, const float* __restrict__ g2p,
                          unsigned short* __restrict__ ctxh, unsigned short* __restrict__ ctxl){
  __shared__ unsigned int ldsT[64*129];        // packed (hi<<16)|lo, [px][c&127]
  int bid = blockIdx.x;                        // p*64 + yo
  int p = bid >> 6, yo = bid & 63;
  int b = p>>2, si = (p>>1)&1, sj = p&1;
  int t = threadIdx.x;
  int cq = t >> 6, px = t & 63;
  float g1 = *g1p, g2 = *g2p;
  // rotate(+45) source coords for dest (yo,px)
  const float cth = 0.70710678118654752f;      // cos45 = sin45
  float fx = (float)px - 31.5f, fy = (float)yo - 31.5f;
  float sx = cth*fx + cth*fy + 31.5f;
  float sy = cth*fy - cth*fx + 31.5f;
  float rx = rintf(sx), ry = rintf(sy);
  bool rvalid = (rx >= 0.f && rx < 64.f && ry >= 0.f && ry < 64.f);
  int roff = rvalid ? (((int)ry)*64 + (int)rx) : 0;
  const float* o1p = o1 + (size_t)p*CC*NPIX + yo*64 + px;
  const float* o2p = o2 + (size_t)p*CC*NPIX + roff;
  const float* xp  = x + ((size_t)(b*CC)*HIMG + si*64 + yo)*WIMG + sj*64 + px;
  const float* gp  = gca + (size_t)b*CC*4 + si*2 + sj;
  size_t obase = (((size_t)(b*HIMG + si*64 + yo))*WIMG + sj*64)*CC;   // + px*CC + c

  for (int half=0; half<2; ++half){
    __syncthreads();
    for (int it=0; it<32; ++it){
      int c = half*128 + it*4 + cq;
      float o1v = o1p[(size_t)c*NPIX];
      float o2v = rvalid ? g2*o2p[(size_t)c*NPIX] : 0.f;
      float xv  = xp[(size_t)c*HIMG*WIMG];
      float gate = gp[(size_t)c*4];
      float val = (g1*o1v + o2v + xv) * gate;
      unsigned short h = f2bf(val);
      float hf = __uint_as_float((unsigned)h << 16);
      unsigned short l = f2bf(val - hf);
      ldsT[px*129 + (c & 127)] = ((unsigned)h << 16) | (unsigned)l;
    }
    __syncthreads();
    for (int base=0; base<8192; base += 2048){
      int idx = base + t*8;
      int ppx = idx >> 7, cl = idx & 127;
      u16x8 hv, lv;
      #pragma unroll
      for (int i=0;i<8;i++){
        unsigned v = ldsT[ppx*129 + cl + i];
        hv[i] = (unsigned short)(v >> 16);
        lv[i] = (unsigned short)(v & 0xffffu);
      }
      size_t g = obase + (size_t)ppx*CC + half*128 + cl;
      *(u16x8*)&ctxh[g] = hv;
      *(u16x8*)&ctxl[g] = lv;
    }
  }
}

// ---------------- 13. conv3x3 as 9 shifted MFMA GEMMs (bf16x3) + BN + residual + relu ----------------
__global__ __launch_bounds__(256) void k_conv_mfma(
    const unsigned short* __restrict__ ctxh, const unsigned short* __restrict__ ctxl,
    const unsigned short* __restrict__ wh, const unsigned short* __restrict__ wlo,
    const float* __restrict__ x,
    const float* __restrict__ cb, const float* __restrict__ bnw, const float* __restrict__ bnb,
    const float* __restrict__ bnm, const float* __restrict__ bnv,
    const float* __restrict__ gmp, float* __restrict__ out){
  __shared__ unsigned short sAh[3*64*40], sAl[3*64*40];   // [tap][co][ci(32)+pad8]
  __shared__ unsigned short sBh[130*40],  sBl[130*40];    // [px(-1..128)][ci(32)+pad8]
  int bid0 = blockIdx.x;                     // 4096; XCD-bijective swizzle
  int lb = (bid0 & 7)*512 + (bid0 >> 3);
  int Y = lb & 127, coc = (lb >> 7) & 3, b = lb >> 9;
  int tid = threadIdx.x, lane = tid & 63, wid = tid >> 6;
  int wm = wid >> 1, wn = wid & 1;           // wave tile: 32co x 64px
  int lrow = lane & 15, lk = lane >> 4;

  f32x4 acc[2][4];
  #pragma unroll
  for (int mf=0;mf<2;mf++)
  #pragma unroll
  for (int nf=0;nf<4;nf++) acc[mf][nf] = (f32x4)0.f;

  for (int dy=0; dy<3; ++dy){
    int Ys = Y + dy - 1;
    bool yok = (unsigned)Ys < 128u;
    size_t rowbase = ((size_t)(b*HIMG + (yok ? Ys : 0)) * WIMG) * CC;
    for (int ks=0; ks<8; ++ks){
      int ci0 = ks*32;
      __syncthreads();
      for (int j = tid; j < 1288; j += 256){
        if (j < 520){
          int px = j >> 2, qq = j & 3;            // px row 0..129 -> Xs = px-1
          int Xs = px - 1;
          int lidx = px*40 + qq*8;
          if (yok && (unsigned)Xs < 128u){
            size_t g = rowbase + (size_t)Xs*CC + ci0 + qq*8;
            *(u16x8*)&sBh[lidx] = *(const u16x8*)&ctxh[g];
            *(u16x8*)&sBl[lidx] = *(const u16x8*)&ctxl[g];
          } else {
            u16x8 z = (u16x8)0;
            *(u16x8*)&sBh[lidx] = z;
            *(u16x8*)&sBl[lidx] = z;
          }
        } else {
          int ja = j - 520;                       // 0..767
          int t3 = ja >> 8;                       // dxi 0..2
          int co = (ja >> 2) & 63, qq = ja & 3;
          size_t g = ((size_t)((dy*3 + t3)*CC + coc*64 + co))*CC + ci0 + qq*8;
          int lidx = (t3*64 + co)*40 + qq*8;
          *(u16x8*)&sAh[lidx] = *(const u16x8*)&wh[g];
          *(u16x8*)&sAl[lidx] = *(const u16x8*)&wlo[g];
        }
      }
      __syncthreads();
      #pragma unroll
      for (int dxi=0; dxi<3; ++dxi){
        bf16x8 a_h[2], a_l[2], b_h[4], b_l[4];
        #pragma unroll
        for (int mf=0; mf<2; ++mf){
          int off = (dxi*64 + wm*32 + mf*16 + lrow)*40 + lk*8;
          a_h[mf] = *(const bf16x8*)&sAh[off];
          a_l[mf] = *(const bf16x8*)&sAl[off];
        }
        #pragma unroll
        for (int nf=0; nf<4; ++nf){
          int off = (wn*64 + nf*16 + lrow + dxi)*40 + lk*8;
          b_h[nf] = *(const bf16x8*)&sBh[off];
          b_l[nf] = *(const bf16x8*)&sBl[off];
        }
        #pragma unroll
        for (int mf=0; mf<2; ++mf)
        #pragma unroll
        for (int nf=0; nf<4; ++nf){
          acc[mf][nf] = __builtin_amdgcn_mfma_f32_16x16x32_bf16(a_h[mf], b_h[nf], acc[mf][nf], 0,0,0);
          acc[mf][nf] = __builtin_amdgcn_mfma_f32_16x16x32_bf16(a_h[mf], b_l[nf], acc[mf][nf], 0,0,0);
          acc[mf][nf] = __builtin_amdgcn_mfma_f32_16x16x32_bf16(a_l[mf], b_h[nf], acc[mf][nf], 0,0,0);
        }
      }
    }
  }
  float gm = *gmp;
  #pragma unroll
  for (int mf=0; mf<2; ++mf){
    #pragma unroll
    for (int r=0; r<4; ++r){
      int co = coc*64 + wm*32 + mf*16 + lk*4 + r;
      float sc = bnw[co] * rsqrtf(bnv[co] + 1e-5f);
      float sh = bnb[co] - bnm[co]*sc;
      float cbv = cb[co];
      #pragma unroll
      for (int nf=0; nf<4; ++nf){
        int px = wn*64 + nf*16 + lrow;
        float yv = (acc[mf][nf][r] + cbv)*sc + sh;
        size_t xi = ((size_t)(b*CC + co)*HIMG + Y)*WIMG + px;
        out[xi] = fmaxf(gm*yv + x[xi], 0.f);
      }
    }
  }
}

// ---------------- launcher ----------------
extern "C" void kernel_launch(void* const* d_in, const int* in_sizes, int n_in,
                              void* d_out, int out_size, void* d_ws, size_t ws_size,
                              hipStream_t stream){
  (void)in_sizes; (void)n_in; (void)out_size; (void)ws_size;
  const float* x   = (const float*)d_in[0];
  const float* wq  = (const float*)d_in[1];
  const float* bq  = (const float*)d_in[2];
  const float* wk  = (const float*)d_in[3];
  const float* bk  = (const float*)d_in[4];
  const float* wv  = (const float*)d_in[5];
  const float* bv  = (const float*)d_in[6];
  const float* g1  = (const float*)d_in[7];
  const float* g2  = (const float*)d_in[8];
  const float* nq_w= (const float*)d_in[9];
  const float* nq_b= (const float*)d_in[10];
  const float* nk_w= (const float*)d_in[11];
  const float* nk_b= (const float*)d_in[12];
  const float* nv_w= (const float*)d_in[13];
  const float* nv_b= (const float*)d_in[14];
  const float* nlg = (const float*)d_in[15];
  const float* cw  = (const float*)d_in[16];
  const float* cb  = (const float*)d_in[17];
  const float* bnw = (const float*)d_in[18];
  const float* bnb = (const float*)d_in[19];
  const float* bnm = (const float*)d_in[20];
  const float* bnv = (const float*)d_in[21];
  const float* gam = (const float*)d_in[22];

  // ws layout (floats); total 125,845,504 floats ~= 503 MB (unchanged from R1)
  float* ws  = (float*)d_ws;
  float* o1  = ws;                    // 33,554,432  : branch1 cc output
  float* b2  = ws + 33554432;         // 33,554,432  : xr -> branch2 cc output
  float* vb  = ws + 67108864;         // 33,554,432  : v (per branch); later ctx_hi/lo bf16
  float* att = ws + 100663296;        // 16,777,216  : logits/att (per branch)
  float* qb  = ws + 117440512;        //  4,194,304  : q; later cwt hi/lo bf16
  float* kb  = ws + 121634816;        //  4,194,304
  float* pooled = ws + 125829120;     //  8,192
  float* gcab   = ws + 125837312;     //  8,192

  unsigned short* ctx_hi = (unsigned short*)vb;                  // 33.5M bf16
  unsigned short* ctx_lo = (unsigned short*)vb + 33554432;       // 33.5M bf16
  unsigned short* cwt_hi = (unsigned short*)qb;                  // 589,824 bf16
  unsigned short* cwt_lo = (unsigned short*)qb + 589824;

  k_pool<<<8192,256,0,stream>>>(x, pooled);
  k_gca<<<8,256,0,stream>>>(pooled, nq_w,nq_b, nk_w,nk_b, nv_w,nv_b, nlg, gcab);
  k_rot_in<<<8192,256,0,stream>>>(x, b2);

  // branch 1: criss-cross on original patches (view 0 = strided patch view of x)
  k_proj_qk<<<512,256,0,stream>>>(x, 0, wq,bq, wk,bk, qb, kb);
  k_eH<<<2048,256,0,stream>>>(qb, kb, att);
  k_eW<<<2048,256,0,stream>>>(qb, kb, att);
  k_softmax<<<32768,256,0,stream>>>(att);
  k_proj_v<<<2048,256,0,stream>>>(x, 0, wv, bv, vb);
  k_oW<<<2048,256,0,stream>>>(vb, att, o1);
  k_oH<<<2048,256,0,stream>>>(vb, att, o1);

  // branch 2: criss-cross on rotated patches (view 1 = contiguous xr in b2)
  k_proj_qk<<<512,256,0,stream>>>(b2, 1, wq,bq, wk,bk, qb, kb);
  k_eH<<<2048,256,0,stream>>>(qb, kb, att);
  k_eW<<<2048,256,0,stream>>>(qb, kb, att);
  k_softmax<<<32768,256,0,stream>>>(att);
  k_proj_v<<<2048,256,0,stream>>>(b2, 1, wv, bv, vb);
  k_oW<<<2048,256,0,stream>>>(vb, att, b2);   // overwrites xr (dead after projections)
  k_oH<<<2048,256,0,stream>>>(vb, att, b2);

  // weights split into qb region (q/k dead after branch-2 eH/eW)
  k_wsplit<<<2304,256,0,stream>>>(cw, cwt_hi, cwt_lo);
  // combine -> NHWC bf16 hi/lo into vb region (v dead after oH)
  k_combine<<<2048,256,0,stream>>>(x, o1, b2, gcab, g1, g2, ctx_hi, ctx_lo);
  // conv via MFMA
  k_conv_mfma<<<4096,256,0,stream>>>(ctx_hi, ctx_lo, cwt_hi, cwt_lo, x,
                                     cb, bnw, bnb, bnm, bnv, gam, (float*)d_out);
}

// Round 8
// 2229.588 us; speedup vs baseline: 2.9615x; 1.6444x over previous
//
#include <hip/hip_runtime.h>
#include <math.h>

#define CC 256
#define HIMG 128
#define WIMG 128
#define BB 8
#define PP 32
#define NPIX 4096   // 64*64 per patch
#define HS 64

typedef short bf16x8 __attribute__((ext_vector_type(8)));
typedef float f32x4 __attribute__((ext_vector_type(4)));
typedef unsigned short u16x8 __attribute__((ext_vector_type(8)));

static __device__ __forceinline__ unsigned short f2bf(float f){
  unsigned u = __float_as_uint(f);
  unsigned r = (u + 0x7fffu + ((u >> 16) & 1u)) >> 16;
  return (unsigned short)r;
}

// ---------------- wave reduce helpers (wave64) ----------------
static __device__ __forceinline__ float wave_max(float v){
  #pragma unroll
  for (int o=32;o>0;o>>=1) v = fmaxf(v, __shfl_down(v,o));
  return v;
}
static __device__ __forceinline__ float wave_sum(float v){
  #pragma unroll
  for (int o=32;o>0;o>>=1) v += __shfl_down(v,o);
  return v;
}

// ---------------- 1. adaptive max pool to (B,C,2,2) ----------------
__global__ void k_pool(const float* __restrict__ x, float* __restrict__ pooled){
  int blk = blockIdx.x;            // B*C*4 blocks
  int sj = blk & 1, si = (blk>>1)&1;
  int bc = blk >> 2;               // b*C + c
  const float* base = x + (size_t)bc*HIMG*WIMG + (size_t)(si*64)*WIMG + sj*64;
  float m = -INFINITY;
  for (int e = threadIdx.x; e < 4096; e += 256){
    int r = e >> 6, col = e & 63;
    m = fmaxf(m, base[r*WIMG + col]);
  }
  m = wave_max(m);
  __shared__ float sm[4];
  if ((threadIdx.x & 63) == 0) sm[threadIdx.x>>6] = m;
  __syncthreads();
  if (threadIdx.x == 0){
    m = fmaxf(fmaxf(sm[0],sm[1]), fmaxf(sm[2],sm[3]));
    pooled[(size_t)bc*4 + si*2 + sj] = m;
  }
}

// ---------------- 2. nonlocal block on pooled + sigmoid -> gca (B,C,2,2) ----------------
__global__ void k_gca(const float* __restrict__ pooled,
                      const float* __restrict__ nq_w, const float* __restrict__ nq_b,
                      const float* __restrict__ nk_w, const float* __restrict__ nk_b,
                      const float* __restrict__ nv_w, const float* __restrict__ nv_b,
                      const float* __restrict__ nlg, float* __restrict__ gca){
  int b = blockIdx.x;
  int t = threadIdx.x;             // channel
  __shared__ float pld[256][4];
  __shared__ float qs[8][4], ks2[8][4], attn[4][4];
  const float* pb = pooled + (size_t)b*CC*4;
  #pragma unroll
  for (int n=0;n<4;n++) pld[t][n] = pb[t*4+n];
  __syncthreads();
  if (t < 32){
    int j = t>>2, n = t&3;
    float aq = 0.f, ak = 0.f;
    for (int c2=0;c2<256;c2++){ float pv = pld[c2][n]; aq += nq_w[j*256+c2]*pv; ak += nk_w[j*256+c2]*pv; }
    qs[j][n] = aq + nq_b[j];
    ks2[j][n] = ak + nk_b[j];
  }
  __syncthreads();
  if (t < 4){
    int n = t;
    float e[4]; float mx = -INFINITY;
    for (int m2=0;m2<4;m2++){ float s=0.f; for (int j=0;j<8;j++) s += qs[j][n]*ks2[j][m2]; e[m2]=s; mx=fmaxf(mx,s); }
    float den=0.f;
    for (int m2=0;m2<4;m2++){ e[m2] = expf(e[m2]-mx); den += e[m2]; }
    for (int m2=0;m2<4;m2++) attn[n][m2] = e[m2]/den;
  }
  __syncthreads();
  float vv[4];
  #pragma unroll
  for (int m2=0;m2<4;m2++){
    float s = nv_b[t];
    for (int c2=0;c2<256;c2++) s += nv_w[(size_t)t*256+c2]*pld[c2][m2];
    vv[m2] = s;
  }
  float g = *nlg;
  #pragma unroll
  for (int n=0;n<4;n++){
    float o = 0.f;
    #pragma unroll
    for (int m2=0;m2<4;m2++) o += vv[m2]*attn[n][m2];
    float val = g*o + pld[t][n];
    gca[(size_t)b*CC*4 + t*4 + n] = 1.0f/(1.0f + expf(-val));
  }
}

// ---------------- 3. x -> patch NHWC bf16 (xb[p][px][256]) ----------------
__global__ __launch_bounds__(256) void k_xcvt(const float* __restrict__ x, unsigned short* __restrict__ xb){
  __shared__ unsigned int ldsT[64*129];        // [px][c-pair]
  int bid = blockIdx.x;                        // p*64 + yo
  int p = bid >> 6, yo = bid & 63;
  int b = p>>2, si = (p>>1)&1, sj = p&1;
  int t = threadIdx.x;
  int cq = t >> 6, px = t & 63;
  const float* xp = x + ((size_t)(b*CC)*HIMG + si*64 + yo)*WIMG + sj*64 + px;
  for (int it=0; it<32; ++it){
    int pr = it*4 + cq;                        // c-pair 0..127
    float v0 = xp[(size_t)(2*pr)*16384];
    float v1 = xp[(size_t)(2*pr+1)*16384];
    ldsT[px*129 + pr] = (unsigned)f2bf(v0) | ((unsigned)f2bf(v1) << 16);
  }
  __syncthreads();
  size_t obase = ((size_t)p*4096 + yo*64)*256;
  for (int it=0; it<8; ++it){
    int idx = it*256 + t;                      // 0..2047 : 64 px * 32 vec
    int ppx = idx >> 5, p4 = (idx & 31)*4;     // vec covers c-pairs p4..p4+3
    u16x8 v;
    #pragma unroll
    for (int i=0;i<4;i++){
      unsigned u = ldsT[ppx*129 + p4 + i];
      v[2*i]   = (unsigned short)(u & 0xffffu);
      v[2*i+1] = (unsigned short)(u >> 16);
    }
    *(u16x8*)&xb[obase + (size_t)ppx*256 + p4*2] = v;
  }
}

// ---------------- 4. rotate -45 by copying channel vectors (bf16 NHWC) ----------------
__global__ void k_rotb(const unsigned short* __restrict__ xb, unsigned short* __restrict__ xrb){
  const float th = -45.0f * 0.017453292519943295f;
  const float cth = cosf(th), sth = sinf(th);
  int bid = blockIdx.x;                        // p*64 + yo
  int p = bid >> 6, yo = bid & 63;
  int t = threadIdx.x;
  int c8 = t & 31, xg = t >> 5;
  float fy = (float)yo - 31.5f;
  for (int pass=0; pass<8; ++pass){
    int xo = pass*8 + xg;
    float fx = (float)xo - 31.5f;
    float sx = cth*fx + sth*fy + 31.5f;
    float sy = cth*fy - sth*fx + 31.5f;
    float rx = rintf(sx), ry = rintf(sy);
    u16x8 v = (u16x8)0;
    if (rx >= 0.f && rx < 64.f && ry >= 0.f && ry < 64.f){
      int spx = ((int)ry)*64 + (int)rx;
      v = *(const u16x8*)&xb[(size_t)p*1048576 + (size_t)spx*256 + c8*8];
    }
    *(u16x8*)&xrb[(size_t)p*1048576 + ((size_t)yo*64 + xo)*256 + c8*8] = v;
  }
}

// ---------------- 5. q,k projection via MFMA -> qb/kb[p][px][32] bf16 ----------------
// (weights converted fp32->bf16 inline during staging; wq/wk are L2-resident)
__global__ __launch_bounds__(256) void k_proj_qk_mfma(const unsigned short* __restrict__ xb,
    const float* __restrict__ wq, const float* __restrict__ wk,
    const float* __restrict__ bq, const float* __restrict__ bk,
    unsigned short* __restrict__ q, unsigned short* __restrict__ k){
  __shared__ unsigned short smem[9216];        // sA[64][40]+sB[128][40] | sT[128][72]
  unsigned short* sA = smem;
  unsigned short* sB = smem + 2560;
  int bid = blockIdx.x;                        // 1024
  int lb = (bid & 7)*128 + (bid >> 3);
  int p = lb >> 5, pxt = lb & 31;
  int px0 = pxt*128;
  int tid = threadIdx.x, lane = tid & 63, wid = tid >> 6;
  int om = wid >> 1, on = wid & 1;
  int lrow = lane & 15, lk = lane >> 4;
  f32x4 acc[2][4];
  #pragma unroll
  for (int mf=0;mf<2;mf++)
  #pragma unroll
  for (int nf=0;nf<4;nf++) acc[mf][nf] = (f32x4)0.f;
  size_t xbase = (size_t)p*1048576 + (size_t)px0*256;
  for (int ks=0; ks<8; ++ks){
    int ci0 = ks*32;
    __syncthreads();
    { int o = tid >> 2, qq = tid & 3;
      const float* wp = (o < 32) ? (wq + o*256 + ci0 + qq*8) : (wk + (o-32)*256 + ci0 + qq*8);
      u16x8 v;
      #pragma unroll
      for (int i=0;i<8;i++) v[i] = f2bf(wp[i]);
      *(u16x8*)&sA[o*40 + qq*8] = v; }
    for (int j = tid; j < 512; j += 256){
      int r = j >> 2, qq = j & 3;
      *(u16x8*)&sB[r*40 + qq*8] = *(const u16x8*)&xb[xbase + (size_t)r*256 + ci0 + qq*8];
    }
    __syncthreads();
    bf16x8 a[2], b[4];
    #pragma unroll
    for (int mf=0; mf<2; ++mf) a[mf] = *(const bf16x8*)&sA[(om*32 + mf*16 + lrow)*40 + lk*8];
    #pragma unroll
    for (int nf=0; nf<4; ++nf) b[nf] = *(const bf16x8*)&sB[(on*64 + nf*16 + lrow)*40 + lk*8];
    #pragma unroll
    for (int mf=0; mf<2; ++mf)
    #pragma unroll
    for (int nf=0; nf<4; ++nf)
      acc[mf][nf] = __builtin_amdgcn_mfma_f32_16x16x32_bf16(a[mf], b[nf], acc[mf][nf], 0,0,0);
  }
  __syncthreads();
  unsigned short* sT = smem;                   // [128][72]
  #pragma unroll
  for (int mf=0; mf<2; ++mf)
  #pragma unroll
  for (int nf=0; nf<4; ++nf)
  #pragma unroll
  for (int r=0; r<4; ++r){
    int oc = om*32 + mf*16 + lk*4 + r;
    int px = on*64 + nf*16 + lrow;
    float bias = (oc < 32) ? bq[oc] : bk[oc-32];
    sT[px*72 + oc] = f2bf(acc[mf][nf][r] + bias);
  }
  __syncthreads();
  for (int j = tid; j < 1024; j += 256){
    int px = j >> 3, s = j & 7;
    u16x8 v = *(u16x8*)&sT[px*72 + s*8];
    size_t oaddr = (size_t)p*131072 + (size_t)(px0+px)*32 + (s&3)*8;
    if (s < 4) *(u16x8*)&q[oaddr] = v;
    else       *(u16x8*)&k[oaddr] = v;
  }
}

// ---------------- 6. v projection via MFMA -> Vb[p][256][4096] bf16 NCHW ----------------
__global__ __launch_bounds__(256) void k_proj_v_mfma(const unsigned short* __restrict__ xb,
    const float* __restrict__ wv, const float* __restrict__ bv,
    unsigned short* __restrict__ vout){
  __shared__ unsigned short smem[18432];       // sA[256][40]+sB[64][40] | sT[256][72]
  unsigned short* sA = smem;
  unsigned short* sB = smem + 10240;
  int bid = blockIdx.x;                        // 2048
  int lb = (bid & 7)*256 + (bid >> 3);
  int p = lb >> 6, pxt = lb & 63;
  int px0 = pxt*64;
  int tid = threadIdx.x, lane = tid & 63, wm = tid >> 6;
  int lrow = lane & 15, lk = lane >> 4;
  f32x4 acc[4][4];
  #pragma unroll
  for (int mf=0;mf<4;mf++)
  #pragma unroll
  for (int nf=0;nf<4;nf++) acc[mf][nf] = (f32x4)0.f;
  size_t xbase = (size_t)p*1048576 + (size_t)px0*256;
  for (int ks=0; ks<8; ++ks){
    int ci0 = ks*32;
    __syncthreads();
    for (int j = tid; j < 1280; j += 256){
      if (j < 1024){
        int co = j >> 2, qq = j & 3;
        const float* wp = wv + (size_t)co*256 + ci0 + qq*8;
        u16x8 v;
        #pragma unroll
        for (int i=0;i<8;i++) v[i] = f2bf(wp[i]);
        *(u16x8*)&sA[co*40 + qq*8] = v;
      } else {
        int jb = j - 1024;
        int r = jb >> 2, qq = jb & 3;
        *(u16x8*)&sB[r*40 + qq*8] = *(const u16x8*)&xb[xbase + (size_t)r*256 + ci0 + qq*8];
      }
    }
    __syncthreads();
    bf16x8 a[4], b[4];
    #pragma unroll
    for (int mf=0; mf<4; ++mf) a[mf] = *(const bf16x8*)&sA[(wm*64 + mf*16 + lrow)*40 + lk*8];
    #pragma unroll
    for (int nf=0; nf<4; ++nf) b[nf] = *(const bf16x8*)&sB[(nf*16 + lrow)*40 + lk*8];
    #pragma unroll
    for (int mf=0; mf<4; ++mf)
    #pragma unroll
    for (int nf=0; nf<4; ++nf)
      acc[mf][nf] = __builtin_amdgcn_mfma_f32_16x16x32_bf16(a[mf], b[nf], acc[mf][nf], 0,0,0);
  }
  __syncthreads();
  unsigned short* sT = smem;                   // [256][72]
  #pragma unroll
  for (int mf=0; mf<4; ++mf)
  #pragma unroll
  for (int nf=0; nf<4; ++nf)
  #pragma unroll
  for (int r=0; r<4; ++r){
    int co = wm*64 + mf*16 + lk*4 + r;
    int px = nf*16 + lrow;
    sT[co*72 + px] = f2bf(acc[mf][nf][r] + bv[co]);
  }
  __syncthreads();
  for (int j = tid; j < 2048; j += 256){
    int co = j >> 3, s = j & 7;
    *(u16x8*)&vout[(size_t)p*1048576 + (size_t)co*4096 + px0 + s*8] = *(u16x8*)&sT[co*72 + s*8];
  }
}

// ---------------- 7. Vb -> Vt2[p][w][c][g] (64x64-tiled transpose) ----------------
__global__ void k_vt(const unsigned short* __restrict__ Vb, unsigned short* __restrict__ Vt2){
  __shared__ unsigned short sT[64*72];
  int bid = blockIdx.x;                        // 8192: p*256 + cgt
  int p = bid >> 8, cgt = bid & 255;
  int cg0 = cgt*64;
  int t = threadIdx.x;
  for (int j = t; j < 512; j += 256){
    int r = j >> 3, s = j & 7;
    *(u16x8*)&sT[r*72 + s*8] = *(const u16x8*)&Vb[(size_t)p*1048576 + (size_t)(cg0+r)*64 + s*8];
  }
  __syncthreads();
  for (int j = t; j < 512; j += 256){
    int w = j >> 3, r0 = (j & 7)*8;
    u16x8 v;
    #pragma unroll
    for (int i=0;i<8;i++) v[i] = sT[(r0+i)*72 + w];
    *(u16x8*)&Vt2[(size_t)p*1048576 + (size_t)w*16384 + cg0 + r0] = v;
  }
}

// ---------------- 8. eH logits via MFMA (diag masked) ----------------
__global__ __launch_bounds__(256) void k_eH_mfma(const unsigned short* __restrict__ qb,
    const unsigned short* __restrict__ kb, float* __restrict__ att){
  __shared__ unsigned short sQ[2560], sK[2560]; // [64][40]
  int bid = blockIdx.x;                        // 2048
  int lb = (bid & 7)*256 + (bid >> 3);
  int p = lb >> 6, w = lb & 63;
  int tid = threadIdx.x, lane = tid & 63, wid = tid >> 6;
  int wm = wid >> 1, wn = wid & 1;
  int lrow = lane & 15, lk = lane >> 4;
  for (int j = tid; j < 512; j += 256){
    if (j < 256){
      int h = j >> 2, qq = j & 3;
      *(u16x8*)&sQ[h*40 + qq*8] = *(const u16x8*)&qb[(size_t)p*131072 + (size_t)(h*64 + w)*32 + qq*8];
    } else {
      int jb = j - 256;
      int g = jb >> 2, qq = jb & 3;
      *(u16x8*)&sK[g*40 + qq*8] = *(const u16x8*)&kb[(size_t)p*131072 + (size_t)(g*64 + w)*32 + qq*8];
    }
  }
  __syncthreads();
  f32x4 acc[2][2];
  #pragma unroll
  for (int mf=0;mf<2;mf++)
  #pragma unroll
  for (int nf=0;nf<2;nf++) acc[mf][nf] = (f32x4)0.f;
  bf16x8 a[2], b[2];
  #pragma unroll
  for (int mf=0; mf<2; ++mf) a[mf] = *(const bf16x8*)&sQ[(wm*32 + mf*16 + lrow)*40 + lk*8];
  #pragma unroll
  for (int nf=0; nf<2; ++nf) b[nf] = *(const bf16x8*)&sK[(wn*32 + nf*16 + lrow)*40 + lk*8];
  #pragma unroll
  for (int mf=0; mf<2; ++mf)
  #pragma unroll
  for (int nf=0; nf<2; ++nf)
    acc[mf][nf] = __builtin_amdgcn_mfma_f32_16x16x32_bf16(a[mf], b[nf], acc[mf][nf], 0,0,0);
  #pragma unroll
  for (int mf=0; mf<2; ++mf)
  #pragma unroll
  for (int nf=0; nf<2; ++nf)
  #pragma unroll
  for (int r=0; r<4; ++r){
    int h = wm*32 + mf*16 + lk*4 + r;
    int g = wn*32 + nf*16 + lrow;
    float e = acc[mf][nf][r];
    if (g == h) e = -1e30f;
    att[((size_t)p*4096 + h*64 + w)*128 + g] = e;
  }
}

// ---------------- 9. eW logits via MFMA ----------------
__global__ __launch_bounds__(256) void k_eW_mfma(const unsigned short* __restrict__ qb,
    const unsigned short* __restrict__ kb, float* __restrict__ att){
  __shared__ unsigned short sQ[2560], sK[2560]; // [64][40]
  int bid = blockIdx.x;                        // 2048
  int lb = (bid & 7)*256 + (bid >> 3);
  int p = lb >> 6, h = lb & 63;
  int tid = threadIdx.x, lane = tid & 63, wid = tid >> 6;
  int wm = wid >> 1, wn = wid & 1;
  int lrow = lane & 15, lk = lane >> 4;
  size_t rbase = (size_t)p*131072 + (size_t)h*2048;
  for (int j = tid; j < 512; j += 256){
    if (j < 256){
      int wv = j >> 2, qq = j & 3;
      *(u16x8*)&sQ[wv*40 + qq*8] = *(const u16x8*)&qb[rbase + (size_t)wv*32 + qq*8];
    } else {
      int jb = j - 256;
      int wv = jb >> 2, qq = jb & 3;
      *(u16x8*)&sK[wv*40 + qq*8] = *(const u16x8*)&kb[rbase + (size_t)wv*32 + qq*8];
    }
  }
  __syncthreads();
  f32x4 acc[2][2];
  #pragma unroll
  for (int mf=0;mf<2;mf++)
  #pragma unroll
  for (int nf=0;nf<2;nf++) acc[mf][nf] = (f32x4)0.f;
  bf16x8 a[2], b[2];
  #pragma unroll
  for (int mf=0; mf<2; ++mf) a[mf] = *(const bf16x8*)&sQ[(wm*32 + mf*16 + lrow)*40 + lk*8];
  #pragma unroll
  for (int nf=0; nf<2; ++nf) b[nf] = *(const bf16x8*)&sK[(wn*32 + nf*16 + lrow)*40 + lk*8];
  #pragma unroll
  for (int mf=0; mf<2; ++mf)
  #pragma unroll
  for (int nf=0; nf<2; ++nf)
    acc[mf][nf] = __builtin_amdgcn_mfma_f32_16x16x32_bf16(a[mf], b[nf], acc[mf][nf], 0,0,0);
  #pragma unroll
  for (int mf=0; mf<2; ++mf)
  #pragma unroll
  for (int nf=0; nf<2; ++nf)
  #pragma unroll
  for (int r=0; r<4; ++r){
    int wv = wm*32 + mf*16 + lk*4 + r;
    int v  = wn*32 + nf*16 + lrow;
    att[((size_t)p*4096 + h*64 + wv)*128 + 64 + v] = acc[mf][nf][r];
  }
}

// ---------------- 10. softmax over 128 logits -> attb bf16 ----------------
__global__ void k_softmax(const float* __restrict__ att, unsigned short* __restrict__ attb){
  int row = blockIdx.x*4 + (threadIdx.x >> 6);    // 131072 rows
  int lane = threadIdx.x & 63;
  const float* rp = att + (size_t)row*128;
  float v0 = rp[lane], v1 = rp[lane+64];
  float m = wave_max(fmaxf(v0,v1));
  m = __shfl(m, 0);
  float e0 = expf(v0 - m), e1 = expf(v1 - m);
  float s = wave_sum(e0 + e1);
  s = __shfl(s, 0);
  unsigned short* ob = attb + (size_t)row*128;
  ob[lane]    = f2bf(e0 / s);
  ob[lane+64] = f2bf(e1 / s);
}

// ---------------- 11. oW via MFMA (initializes out) ----------------
__global__ __launch_bounds__(256) void k_oW_mfma(const unsigned short* __restrict__ v,
    const unsigned short* __restrict__ attb, float* __restrict__ out){
  __shared__ unsigned short sV[10240], sAtt[2560];  // [256][40], [64][40]
  int bid = blockIdx.x;                        // 2048
  int lb = (bid & 7)*256 + (bid >> 3);
  int p = lb >> 6, h = lb & 63;
  int tid = threadIdx.x, lane = tid & 63, wm = tid >> 6;
  int lrow = lane & 15, lk = lane >> 4;
  f32x4 acc[4][4];
  #pragma unroll
  for (int mf=0;mf<4;mf++)
  #pragma unroll
  for (int nf=0;nf<4;nf++) acc[mf][nf] = (f32x4)0.f;
  for (int ks=0; ks<2; ++ks){
    int ci0 = ks*32;
    __syncthreads();
    for (int j = tid; j < 1280; j += 256){
      if (j < 1024){
        int c = j >> 2, qq = j & 3;
        *(u16x8*)&sV[c*40 + qq*8] =
          *(const u16x8*)&v[(size_t)p*1048576 + (size_t)c*4096 + h*64 + ci0 + qq*8];
      } else {
        int jb = j - 1024;
        int r = jb >> 2, qq = jb & 3;
        *(u16x8*)&sAtt[r*40 + qq*8] =
          *(const u16x8*)&attb[(size_t)p*524288 + (size_t)(h*64 + r)*128 + 64 + ci0 + qq*8];
      }
    }
    __syncthreads();
    bf16x8 a[4], b[4];
    #pragma unroll
    for (int mf=0; mf<4; ++mf) a[mf] = *(const bf16x8*)&sV[(wm*64 + mf*16 + lrow)*40 + lk*8];
    #pragma unroll
    for (int nf=0; nf<4; ++nf) b[nf] = *(const bf16x8*)&sAtt[(nf*16 + lrow)*40 + lk*8];
    #pragma unroll
    for (int mf=0; mf<4; ++mf)
    #pragma unroll
    for (int nf=0; nf<4; ++nf)
      acc[mf][nf] = __builtin_amdgcn_mfma_f32_16x16x32_bf16(a[mf], b[nf], acc[mf][nf], 0,0,0);
  }
  #pragma unroll
  for (int mf=0; mf<4; ++mf)
  #pragma unroll
  for (int nf=0; nf<4; ++nf)
  #pragma unroll
  for (int r=0; r<4; ++r){
    int c = wm*64 + mf*16 + lk*4 + r;
    int wcol = nf*16 + lrow;
    out[(size_t)p*1048576 + (size_t)c*4096 + h*64 + wcol] = acc[mf][nf][r];
  }
}

// ---------------- 12. oH via MFMA (accumulates into out) ----------------
__global__ __launch_bounds__(256) void k_oH_mfma(const unsigned short* __restrict__ vt,
    const unsigned short* __restrict__ attb, float* __restrict__ out){
  __shared__ unsigned short sV[10240], sAtt[2560];  // [256][40], [64][40]
  int bid = blockIdx.x;                        // 2048
  int lb = (bid & 7)*256 + (bid >> 3);
  int p = lb >> 6, w = lb & 63;
  int tid = threadIdx.x, lane = tid & 63, wm = tid >> 6;
  int lrow = lane & 15, lk = lane >> 4;
  f32x4 acc[4][4];
  #pragma unroll
  for (int mf=0;mf<4;mf++)
  #pragma unroll
  for (int nf=0;nf<4;nf++) acc[mf][nf] = (f32x4)0.f;
  for (int ks=0; ks<2; ++ks){
    int ci0 = ks*32;
    __syncthreads();
    for (int j = tid; j < 1280; j += 256){
      if (j < 1024){
        int c = j >> 2, qq = j & 3;
        *(u16x8*)&sV[c*40 + qq*8] =
          *(const u16x8*)&vt[(size_t)p*1048576 + (size_t)w*16384 + (size_t)c*64 + ci0 + qq*8];
      } else {
        int jb = j - 1024;
        int hh = jb >> 2, qq = jb & 3;
        *(u16x8*)&sAtt[hh*40 + qq*8] =
          *(const u16x8*)&attb[(size_t)p*524288 + (size_t)(hh*64 + w)*128 + ci0 + qq*8];
      }
    }
    __syncthreads();
    bf16x8 a[4], b[4];
    #pragma unroll
    for (int mf=0; mf<4; ++mf) a[mf] = *(const bf16x8*)&sV[(wm*64 + mf*16 + lrow)*40 + lk*8];
    #pragma unroll
    for (int nf=0; nf<4; ++nf) b[nf] = *(const bf16x8*)&sAtt[(nf*16 + lrow)*40 + lk*8];
    #pragma unroll
    for (int mf=0; mf<4; ++mf)
    #pragma unroll
    for (int nf=0; nf<4; ++nf)
      acc[mf][nf] = __builtin_amdgcn_mfma_f32_16x16x32_bf16(a[mf], b[nf], acc[mf][nf], 0,0,0);
  }
  #pragma unroll
  for (int mf=0; mf<4; ++mf)
  #pragma unroll
  for (int nf=0; nf<4; ++nf)
  #pragma unroll
  for (int r=0; r<4; ++r){
    int c = wm*64 + mf*16 + lk*4 + r;
    int hh = nf*16 + lrow;
    out[(size_t)p*1048576 + (size_t)c*4096 + hh*64 + w] += acc[mf][nf][r];
  }
}

// ---------------- 13. weight split: cw fp32 -> [tap][co][ci] bf16 hi/lo ----------------
__global__ void k_wsplit(const float* __restrict__ cw, unsigned short* __restrict__ wh,
                         unsigned short* __restrict__ wlo){
  int idx = blockIdx.x*256 + threadIdx.x;      // 2304 blocks -> 589824
  if (idx >= 9*256*256) return;
  int tap = idx >> 16;         // 0..8
  int rem = idx & 65535;       // co*256+ci
  float w = cw[(size_t)rem*9 + tap];
  unsigned short h = f2bf(w);
  float hf = __uint_as_float((unsigned)h << 16);
  wh[idx] = h;
  wlo[idx] = f2bf(w - hf);
}

// ---------------- 14. combine: ctx = (g1*o1 + rot45(g2*o2) + x) * gate -> NHWC bf16 hi/lo ----------------
__global__ __launch_bounds__(256) void k_combine(const float* __restrict__ x, const float* __restrict__ o1,
                          const float* __restrict__ o2, const float* __restrict__ gca,
                          const float* __restrict__ g1p, const float* __restrict__ g2p,
                          unsigned short* __restrict__ ctxh, unsigned short* __restrict__ ctxl){
  __shared__ unsigned int ldsT[64*129];        // packed (hi<<16)|lo, [px][c&127]
  int bid = blockIdx.x;                        // p*64 + yo
  int p = bid >> 6, yo = bid & 63;
  int b = p>>2, si = (p>>1)&1, sj = p&1;
  int t = threadIdx.x;
  int cq = t >> 6, px = t & 63;
  float g1 = *g1p, g2 = *g2p;
  const float cth = 0.70710678118654752f;      // cos45 = sin45
  float fx = (float)px - 31.5f, fy = (float)yo - 31.5f;
  float sx = cth*fx + cth*fy + 31.5f;
  float sy = cth*fy - cth*fx + 31.5f;
  float rx = rintf(sx), ry = rintf(sy);
  bool rvalid = (rx >= 0.f && rx < 64.f && ry >= 0.f && ry < 64.f);
  int roff = rvalid ? (((int)ry)*64 + (int)rx) : 0;
  const float* o1p = o1 + (size_t)p*CC*NPIX + yo*64 + px;
  const float* o2p = o2 + (size_t)p*CC*NPIX + roff;
  const float* xp  = x + ((size_t)(b*CC)*HIMG + si*64 + yo)*WIMG + sj*64 + px;
  const float* gp  = gca + (size_t)b*CC*4 + si*2 + sj;
  size_t obase = (((size_t)(b*HIMG + si*64 + yo))*WIMG + sj*64)*CC;   // + px*CC + c

  for (int half=0; half<2; ++half){
    __syncthreads();
    for (int it=0; it<32; ++it){
      int c = half*128 + it*4 + cq;
      float o1v = o1p[(size_t)c*NPIX];
      float o2v = rvalid ? g2*o2p[(size_t)c*NPIX] : 0.f;
      float xv  = xp[(size_t)c*HIMG*WIMG];
      float gate = gp[(size_t)c*4];
      float val = (g1*o1v + o2v + xv) * gate;
      unsigned short h = f2bf(val);
      float hf = __uint_as_float((unsigned)h << 16);
      unsigned short l = f2bf(val - hf);
      ldsT[px*129 + (c & 127)] = ((unsigned)h << 16) | (unsigned)l;
    }
    __syncthreads();
    for (int base=0; base<8192; base += 2048){
      int idx = base + t*8;
      int ppx = idx >> 7, cl = idx & 127;
      u16x8 hv, lv;
      #pragma unroll
      for (int i=0;i<8;i++){
        unsigned v = ldsT[ppx*129 + cl + i];
        hv[i] = (unsigned short)(v >> 16);
        lv[i] = (unsigned short)(v & 0xffffu);
      }
      size_t g = obase + (size_t)ppx*CC + half*128 + cl;
      *(u16x8*)&ctxh[g] = hv;
      *(u16x8*)&ctxl[g] = lv;
    }
  }
}

// ---------------- 15. conv3x3 as 9 shifted MFMA GEMMs (bf16x3) + BN + residual + relu ----------------
__global__ __launch_bounds__(256) void k_conv_mfma(
    const unsigned short* __restrict__ ctxh, const unsigned short* __restrict__ ctxl,
    const unsigned short* __restrict__ wh, const unsigned short* __restrict__ wlo,
    const float* __restrict__ x,
    const float* __restrict__ cb, const float* __restrict__ bnw, const float* __restrict__ bnb,
    const float* __restrict__ bnm, const float* __restrict__ bnv,
    const float* __restrict__ gmp, float* __restrict__ out){
  __shared__ unsigned short sAh[3*64*40], sAl[3*64*40];   // [tap][co][ci(32)+pad8]
  __shared__ unsigned short sBh[130*40],  sBl[130*40];    // [px(-1..128)][ci(32)+pad8]
  int bid0 = blockIdx.x;                     // 4096; XCD-bijective swizzle
  int lb = (bid0 & 7)*512 + (bid0 >> 3);
  int Y = lb & 127, coc = (lb >> 7) & 3, b = lb >> 9;
  int tid = threadIdx.x, lane = tid & 63, wid = tid >> 6;
  int wm = wid >> 1, wn = wid & 1;           // wave tile: 32co x 64px
  int lrow = lane & 15, lk = lane >> 4;

  f32x4 acc[2][4];
  #pragma unroll
  for (int mf=0;mf<2;mf++)
  #pragma unroll
  for (int nf=0;nf<4;nf++) acc[mf][nf] = (f32x4)0.f;

  for (int dy=0; dy<3; ++dy){
    int Ys = Y + dy - 1;
    bool yok = (unsigned)Ys < 128u;
    size_t rowbase = ((size_t)(b*HIMG + (yok ? Ys : 0)) * WIMG) * CC;
    for (int ks=0; ks<8; ++ks){
      int ci0 = ks*32;
      __syncthreads();
      for (int j = tid; j < 1288; j += 256){
        if (j < 520){
          int px = j >> 2, qq = j & 3;            // px row 0..129 -> Xs = px-1
          int Xs = px - 1;
          int lidx = px*40 + qq*8;
          if (yok && (unsigned)Xs < 128u){
            size_t g = rowbase + (size_t)Xs*CC + ci0 + qq*8;
            *(u16x8*)&sBh[lidx] = *(const u16x8*)&ctxh[g];
            *(u16x8*)&sBl[lidx] = *(const u16x8*)&ctxl[g];
          } else {
            u16x8 z = (u16x8)0;
            *(u16x8*)&sBh[lidx] = z;
            *(u16x8*)&sBl[lidx] = z;
          }
        } else {
          int ja = j - 520;                       // 0..767
          int t3 = ja >> 8;                       // dxi 0..2
          int co = (ja >> 2) & 63, qq = ja & 3;
          size_t g = ((size_t)((dy*3 + t3)*CC + coc*64 + co))*CC + ci0 + qq*8;
          int lidx = (t3*64 + co)*40 + qq*8;
          *(u16x8*)&sAh[lidx] = *(const u16x8*)&wh[g];
          *(u16x8*)&sAl[lidx] = *(const u16x8*)&wlo[g];
        }
      }
      __syncthreads();
      #pragma unroll
      for (int dxi=0; dxi<3; ++dxi){
        bf16x8 a_h[2], a_l[2], b_h[4], b_l[4];
        #pragma unroll
        for (int mf=0; mf<2; ++mf){
          int off = (dxi*64 + wm*32 + mf*16 + lrow)*40 + lk*8;
          a_h[mf] = *(const bf16x8*)&sAh[off];
          a_l[mf] = *(const bf16x8*)&sAl[off];
        }
        #pragma unroll
        for (int nf=0; nf<4; ++nf){
          int off = (wn*64 + nf*16 + lrow + dxi)*40 + lk*8;
          b_h[nf] = *(const bf16x8*)&sBh[off];
          b_l[nf] = *(const bf16x8*)&sBl[off];
        }
        #pragma unroll
        for (int mf=0; mf<2; ++mf)
        #pragma unroll
        for (int nf=0; nf<4; ++nf){
          acc[mf][nf] = __builtin_amdgcn_mfma_f32_16x16x32_bf16(a_h[mf], b_h[nf], acc[mf][nf], 0,0,0);
          acc[mf][nf] = __builtin_amdgcn_mfma_f32_16x16x32_bf16(a_h[mf], b_l[nf], acc[mf][nf], 0,0,0);
          acc[mf][nf] = __builtin_amdgcn_mfma_f32_16x16x32_bf16(a_l[mf], b_h[nf], acc[mf][nf], 0,0,0);
        }
      }
    }
  }
  float gm = *gmp;
  #pragma unroll
  for (int mf=0; mf<2; ++mf){
    #pragma unroll
    for (int r=0; r<4; ++r){
      int co = coc*64 + wm*32 + mf*16 + lk*4 + r;
      float sc = bnw[co] * rsqrtf(bnv[co] + 1e-5f);
      float sh = bnb[co] - bnm[co]*sc;
      float cbv = cb[co];
      #pragma unroll
      for (int nf=0; nf<4; ++nf){
        int px = wn*64 + nf*16 + lrow;
        float yv = (acc[mf][nf][r] + cbv)*sc + sh;
        size_t xi = ((size_t)(b*CC + co)*HIMG + Y)*WIMG + px;
        out[xi] = fmaxf(gm*yv + x[xi], 0.f);
      }
    }
  }
}

// ---------------- launcher ----------------
extern "C" void kernel_launch(void* const* d_in, const int* in_sizes, int n_in,
                              void* d_out, int out_size, void* d_ws, size_t ws_size,
                              hipStream_t stream){
  (void)in_sizes; (void)n_in; (void)out_size; (void)ws_size;
  const float* x   = (const float*)d_in[0];
  const float* wq  = (const float*)d_in[1];
  const float* bq  = (const float*)d_in[2];
  const float* wk  = (const float*)d_in[3];
  const float* bk  = (const float*)d_in[4];
  const float* wv  = (const float*)d_in[5];
  const float* bv  = (const float*)d_in[6];
  const float* g1  = (const float*)d_in[7];
  const float* g2  = (const float*)d_in[8];
  const float* nq_w= (const float*)d_in[9];
  const float* nq_b= (const float*)d_in[10];
  const float* nk_w= (const float*)d_in[11];
  const float* nk_b= (const float*)d_in[12];
  const float* nv_w= (const float*)d_in[13];
  const float* nv_b= (const float*)d_in[14];
  const float* nlg = (const float*)d_in[15];
  const float* cw  = (const float*)d_in[16];
  const float* cb  = (const float*)d_in[17];
  const float* bnw = (const float*)d_in[18];
  const float* bnb = (const float*)d_in[19];
  const float* bnm = (const float*)d_in[20];
  const float* bnv = (const float*)d_in[21];
  const float* gam = (const float*)d_in[22];

  // ws layout (floats), total exactly 125,845,504 floats (same as validated R3)
  float* ws  = (float*)d_ws;
  float* o1  = ws;                                                // [0, 33.5M) fp32
  float* o2  = ws + 33554432;                                     // [33.5M, 67.1M) fp32 (written at oW(b2))
  unsigned short* xb1 = (unsigned short*)(ws + 33554432);         // 33.5M sh, dead after proj_v(b1)
  unsigned short* xrb = (unsigned short*)(ws + 50331648);         // 33.5M sh, dead after proj_v(b2)
  unsigned short* qbb = (unsigned short*)(ws + 67108864);         // 4.2M sh, dead after eW
  unsigned short* kbb = (unsigned short*)(ws + 69206016);
  unsigned short* Vb  = (unsigned short*)(ws + 67108864);         // 33.5M sh (after qk dead)
  unsigned short* Vt2 = (unsigned short*)(ws + 83886080);
  unsigned short* ctx_hi = (unsigned short*)(ws + 67108864);      // after branch2 done
  unsigned short* ctx_lo = ctx_hi + 33554432;
  float* att = ws + 100663296;                                    // 16.7M fp32
  unsigned short* cwt_hi = (unsigned short*)(ws + 100663296);     // after softmax(b2): att dead
  unsigned short* cwt_lo = cwt_hi + 589824;
  unsigned short* attb = (unsigned short*)(ws + 117440512);       // 16.7M sh
  float* pooled = ws + 125829120;                                 // 8K
  float* gcab   = ws + 125837312;                                 // 8K

  k_pool<<<8192,256,0,stream>>>(x, pooled);
  k_gca<<<8,256,0,stream>>>(pooled, nq_w,nq_b, nk_w,nk_b, nv_w,nv_b, nlg, gcab);
  k_xcvt<<<2048,256,0,stream>>>(x, xb1);
  k_rotb<<<2048,256,0,stream>>>(xb1, xrb);

  // branch 1 (original patches, xb1)
  k_proj_qk_mfma<<<1024,256,0,stream>>>(xb1, wq, wk, bq, bk, qbb, kbb);
  k_eH_mfma<<<2048,256,0,stream>>>(qbb, kbb, att);
  k_eW_mfma<<<2048,256,0,stream>>>(qbb, kbb, att);
  k_softmax<<<32768,256,0,stream>>>(att, attb);
  k_proj_v_mfma<<<2048,256,0,stream>>>(xb1, wv, bv, Vb);
  k_vt<<<8192,256,0,stream>>>(Vb, Vt2);
  k_oW_mfma<<<2048,256,0,stream>>>(Vb, attb, o1);
  k_oH_mfma<<<2048,256,0,stream>>>(Vt2, attb, o1);

  // branch 2 (rotated patches, xrb)
  k_proj_qk_mfma<<<1024,256,0,stream>>>(xrb, wq, wk, bq, bk, qbb, kbb);
  k_eH_mfma<<<2048,256,0,stream>>>(qbb, kbb, att);
  k_eW_mfma<<<2048,256,0,stream>>>(qbb, kbb, att);
  k_softmax<<<32768,256,0,stream>>>(att, attb);
  k_proj_v_mfma<<<2048,256,0,stream>>>(xrb, wv, bv, Vb);
  k_vt<<<8192,256,0,stream>>>(Vb, Vt2);
  k_oW_mfma<<<2048,256,0,stream>>>(Vb, attb, o2);
  k_oH_mfma<<<2048,256,0,stream>>>(Vt2, attb, o2);

  // conv weights split into att region (att dead after softmax(b2))
  k_wsplit<<<2304,256,0,stream>>>(cw, cwt_hi, cwt_lo);
  // combine -> NHWC bf16 hi/lo into Vb/Vt2 region (dead after oH(b2))
  k_combine<<<2048,256,0,stream>>>(x, o1, o2, gcab, g1, g2, ctx_hi, ctx_lo);
  // conv via MFMA
  k_conv_mfma<<<4096,256,0,stream>>>(ctx_hi, ctx_lo, cwt_hi, cwt_lo, x,
                                     cb, bnw, bnb, bnm, bnv, gam, (float*)d_out);
}